// Round 16
// baseline (114.610 us; speedup 1.0000x reference)
//
#include <hip/hip_runtime.h>
#include <math.h>

// Problem dims
#define NB    2
#define LSEQ  256
#define HDIM  256
#define IDIM  512
#define NROW  512      // NB*LSEQ
#define NC    8        // scan chunks
#define TCH   32       // chunk length (NC*TCH == LSEQ)
#define SQ    4        // s-quarter split (128 s each)

typedef __attribute__((ext_vector_type(8))) short bf16x8;
typedef __attribute__((ext_vector_type(4))) float f32x4;

__device__ inline unsigned short f2b(float f) {
    unsigned u = __float_as_uint(f);
    return (unsigned short)((u + 0x7FFFu + ((u >> 16) & 1u)) >> 16);
}

// ---------------------------------------------------------------------------
// kcvt: bf16 staging: xb[r][h], Wqb[o][h], WgT[h][i], cwb[k][o][i], Wsgb,
// bsg, W_outb. Memory-bound, grid-stride.
// ---------------------------------------------------------------------------
__global__ __launch_bounds__(256) void kcvt(const float* __restrict__ x,
                                            const float* __restrict__ W_in,
                                            const float* __restrict__ conv_w,
                                            const float* __restrict__ W_ssm,
                                            const float* __restrict__ W_gate,
                                            const float* __restrict__ b_ssm,
                                            const float* __restrict__ b_gate,
                                            const float* __restrict__ W_out,
                                            unsigned short* __restrict__ xb,
                                            unsigned short* __restrict__ Wqb,
                                            unsigned short* __restrict__ WgT,
                                            unsigned short* __restrict__ cwb,
                                            unsigned short* __restrict__ Wsgb,
                                            float* __restrict__ bsg,
                                            unsigned short* __restrict__ W_outb) {
    const int stride = gridDim.x * 256;
    const int t0 = blockIdx.x * 256 + threadIdx.x;
    for (int i = t0; i < 131072; i += stride) xb[i] = f2b(x[i]);
    for (int i = t0; i < 131072; i += stride) Wqb[i] = f2b(W_in[i]);
    // WgT[h][i] = W_in[512+i][h]
    for (int d = t0; d < 131072; d += stride) {
        int i = d & 511, h = d >> 9;
        WgT[(size_t)h * 512 + i] = f2b(W_in[(size_t)(512 + i) * 256 + h]);
    }
    // cwb[k][o][i] = conv_w[o][i][k]
    for (int d = t0; d < 262144; d += stride) {
        const float* s = conv_w + (size_t)d * 3;
        cwb[d]          = f2b(s[0]);
        cwb[262144 + d] = f2b(s[1]);
        cwb[524288 + d] = f2b(s[2]);
    }
    // Wsgb rows: 0..1023 = W_ssm[512..1535]; 1024..1535 = W_gate[512..1023]
    for (int d = t0; d < 786432; d += stride) {
        int j = d >> 9, i = d & 511;
        float v = (j < 1024) ? W_ssm[(size_t)(512 + j) * 512 + i]
                             : W_gate[(size_t)(j - 512) * 512 + i];
        Wsgb[d] = f2b(v);
    }
    for (int j = t0; j < 1536; j += stride)
        bsg[j] = (j < 1024) ? b_ssm[512 + j] : b_gate[j - 512];
    for (int i = t0; i < 131072; i += stride) W_outb[i] = f2b(W_out[i]);
}

// ---------------------------------------------------------------------------
// kW: Wcb[k][o][h] = sum_i cwb[k][o][i] * WgT[h][i]  (3 planes share B-frag).
// ---------------------------------------------------------------------------
__global__ __launch_bounds__(256) void kW_mfma(const unsigned short* __restrict__ cwb,
                                               const unsigned short* __restrict__ WgT,
                                               unsigned short* __restrict__ Wcb) {
    const int t = threadIdx.x;
    const int w = blockIdx.x * 4 + (t >> 6);   // 0..511
    const int lane = t & 63;
    const int mt = w >> 4, nt = w & 15;
    const int o0 = mt * 16, h0 = nt * 16;
    const int fr = lane & 15, fk = (lane >> 4) * 8;
    const unsigned short* a0 = cwb + (size_t)(o0 + fr) * 512 + fk;
    const unsigned short* a1 = a0 + 262144;
    const unsigned short* a2 = a0 + 524288;
    const unsigned short* bp = WgT + (size_t)(h0 + fr) * 512 + fk;
    f32x4 ac0 = {0.f, 0.f, 0.f, 0.f};
    f32x4 ac1 = {0.f, 0.f, 0.f, 0.f};
    f32x4 ac2 = {0.f, 0.f, 0.f, 0.f};
    #pragma unroll
    for (int k0 = 0; k0 < 512; k0 += 32) {
        bf16x8 bv = *(const bf16x8*)(bp + k0);
        bf16x8 v0 = *(const bf16x8*)(a0 + k0);
        bf16x8 v1 = *(const bf16x8*)(a1 + k0);
        bf16x8 v2 = *(const bf16x8*)(a2 + k0);
        ac0 = __builtin_amdgcn_mfma_f32_16x16x32_bf16(v0, bv, ac0, 0, 0, 0);
        ac1 = __builtin_amdgcn_mfma_f32_16x16x32_bf16(v1, bv, ac1, 0, 0, 0);
        ac2 = __builtin_amdgcn_mfma_f32_16x16x32_bf16(v2, bv, ac2, 0, 0, 0);
    }
    const int orow = (lane >> 4) * 4;
    const int hc = h0 + fr;
    #pragma unroll
    for (int j = 0; j < 4; ++j) {
        size_t o = (size_t)(o0 + orow + j) * 256 + hc;
        Wcb[o]          = f2b(ac0[j]);
        Wcb[131072 + o] = f2b(ac1[j]);
        Wcb[262144 + o] = f2b(ac2[j]);
    }
}

// ---------------------------------------------------------------------------
// kxc2: xc[r,o] = gelu(x_r·Wq[o]) + sum_k x_{r+k-1}·Wc[k][o] + conv_b[o]
// ---------------------------------------------------------------------------
__global__ __launch_bounds__(256) void kxc2_mfma(const unsigned short* __restrict__ xb,
                                                 const unsigned short* __restrict__ Wqb,
                                                 const unsigned short* __restrict__ Wcb,
                                                 const float* __restrict__ conv_b,
                                                 float* __restrict__ xc,
                                                 unsigned short* __restrict__ xcb) {
    const int t = threadIdx.x;
    const int w = blockIdx.x * 4 + (t >> 6);   // 0..1023
    const int lane = t & 63;
    const int mt = w >> 5, nt = w & 31;
    const int r0 = mt * 16, o0 = nt * 16;
    const int fr = lane & 15, fk = (lane >> 4) * 8;
    const int g = r0 + fr;
    const int lo = r0 & ~255, hi = lo + 256;
    const bool okm = (g - 1 >= lo), okp = (g + 1 < hi);
    const unsigned short* am = xb + (size_t)(g - 1) * 256 + fk;
    const unsigned short* a0 = xb + (size_t)g * 256 + fk;
    const unsigned short* ap = xb + (size_t)(g + 1) * 256 + fk;
    const unsigned short* bq = Wqb + (size_t)(o0 + fr) * 256 + fk;
    const unsigned short* b0 = Wcb + (size_t)(o0 + fr) * 256 + fk;
    const unsigned short* b1 = b0 + 131072;
    const unsigned short* b2 = b0 + 262144;
    const bf16x8 zz = {0, 0, 0, 0, 0, 0, 0, 0};
    f32x4 accq = {0.f, 0.f, 0.f, 0.f};
    f32x4 accc = {0.f, 0.f, 0.f, 0.f};
    #pragma unroll
    for (int k0 = 0; k0 < 256; k0 += 32) {
        bf16x8 avm = okm ? *(const bf16x8*)(am + k0) : zz;
        bf16x8 av0 = *(const bf16x8*)(a0 + k0);
        bf16x8 avp = okp ? *(const bf16x8*)(ap + k0) : zz;
        bf16x8 bqv = *(const bf16x8*)(bq + k0);
        bf16x8 b0v = *(const bf16x8*)(b0 + k0);
        bf16x8 b1v = *(const bf16x8*)(b1 + k0);
        bf16x8 b2v = *(const bf16x8*)(b2 + k0);
        accq = __builtin_amdgcn_mfma_f32_16x16x32_bf16(av0, bqv, accq, 0, 0, 0);
        accc = __builtin_amdgcn_mfma_f32_16x16x32_bf16(avm, b0v, accc, 0, 0, 0);
        accc = __builtin_amdgcn_mfma_f32_16x16x32_bf16(av0, b1v, accc, 0, 0, 0);
        accc = __builtin_amdgcn_mfma_f32_16x16x32_bf16(avp, b2v, accc, 0, 0, 0);
    }
    const int orow = (lane >> 4) * 4;
    const int oc = o0 + fr;
    const float cb = conv_b[oc];
    #pragma unroll
    for (int j = 0; j < 4; ++j) {
        int r = r0 + orow + j;
        float q = accq[j];
        float gl = 0.5f * q * (1.0f + erff(q * 0.70710678118654752f));
        float v = gl + accc[j] + cb;
        xc[(size_t)r * IDIM + oc] = v;
        xcb[(size_t)r * IDIM + oc] = f2b(v);
    }
}

// ---------------------------------------------------------------------------
// k3f: fused ssm/gate GEMM + elementwise; also pre-initializes y = u*D.
// ---------------------------------------------------------------------------
__global__ __launch_bounds__(256) void k3f_mfma(const unsigned short* __restrict__ xcb,
                                                const unsigned short* __restrict__ Wsgb,
                                                const float* __restrict__ bsg,
                                                const float* __restrict__ xc,
                                                const float* __restrict__ D,
                                                float* __restrict__ Cw,
                                                float* __restrict__ u,
                                                float* __restrict__ y) {
    const int t = threadIdx.x;
    const int w = blockIdx.x * 4 + (t >> 6);   // 0..1023
    const int lane = t & 63;
    const int mt = w >> 5, nt = w & 31;
    const int r0 = mt * 16, s0 = nt * 16;
    const int fr = lane & 15, fk = (lane >> 4) * 8;
    const unsigned short* ap = xcb + (size_t)(r0 + fr) * IDIM + fk;
    const unsigned short* b0 = Wsgb + (size_t)(s0 + fr) * IDIM + fk;
    const unsigned short* b1 = Wsgb + (size_t)(512 + s0 + fr) * IDIM + fk;
    const unsigned short* b2 = Wsgb + (size_t)(1024 + s0 + fr) * IDIM + fk;
    f32x4 ac0 = {0.f, 0.f, 0.f, 0.f};
    f32x4 ac1 = {0.f, 0.f, 0.f, 0.f};
    f32x4 ac2 = {0.f, 0.f, 0.f, 0.f};
    #pragma unroll
    for (int k0 = 0; k0 < IDIM; k0 += 32) {
        bf16x8 av  = *(const bf16x8*)(ap + k0);
        bf16x8 bv0 = *(const bf16x8*)(b0 + k0);
        bf16x8 bv1 = *(const bf16x8*)(b1 + k0);
        bf16x8 bv2 = *(const bf16x8*)(b2 + k0);
        ac0 = __builtin_amdgcn_mfma_f32_16x16x32_bf16(av, bv0, ac0, 0, 0, 0);
        ac1 = __builtin_amdgcn_mfma_f32_16x16x32_bf16(av, bv1, ac1, 0, 0, 0);
        ac2 = __builtin_amdgcn_mfma_f32_16x16x32_bf16(av, bv2, ac2, 0, 0, 0);
    }
    const int orow = (lane >> 4) * 4;
    const int sc = s0 + fr;
    const float bc = bsg[sc], bd = bsg[512 + sc], bg = bsg[1024 + sc];
    const float Dv = D[sc];
    #pragma unroll
    for (int j = 0; j < 4; ++j) {
        int r = r0 + orow + j;
        float craw = ac0[j] + bc;
        float dw   = ac1[j] + bd;
        float graw = ac2[j] + bg;
        float gv = 1.0f / (1.0f + expf(-graw));
        float xcv = xc[(size_t)r * IDIM + sc];
        float uv = xcv * dw * dw;
        Cw[(size_t)r * IDIM + sc] = gv * craw;
        u[(size_t)r * IDIM + sc]  = uv;
        y[(size_t)r * IDIM + sc]  = uv * Dv;
    }
}

// ---------------------------------------------------------------------------
// K4a: chunk-local scan, s-quarter split. Wave = (b,c,q,ig): lane owns
// 2 s x 4 i. 8192 waves (8/SIMD). Writes carry to C_loc.
// ---------------------------------------------------------------------------
__global__ __launch_bounds__(256) void k4a_pass1(const float* __restrict__ u,
                                                 const float* __restrict__ A,
                                                 float* __restrict__ C_loc) {
    const int wave = (blockIdx.x * 256 + threadIdx.x) >> 6;  // 0..8191
    const int lane = threadIdx.x & 63;
    const int ig = wave & 127;
    const int q  = (wave >> 7) & (SQ - 1);
    const int c  = (wave >> 9) & (NC - 1);
    const int b  = wave >> 12;
    const int i4 = ig * 4;
    const int s2 = q * 128 + lane * 2;
    float a[2][4], h[2][4];
    #pragma unroll
    for (int k = 0; k < 2; ++k) {
        float4 av = *(const float4*)&A[(size_t)(s2 + k) * IDIM + i4];
        a[k][0] = av.x; a[k][1] = av.y; a[k][2] = av.z; a[k][3] = av.w;
        #pragma unroll
        for (int ii = 0; ii < 4; ++ii) h[k][ii] = 0.f;
    }
    const float* ub = u + ((size_t)b * LSEQ + c * TCH) * IDIM;
    for (int l = 0; l < TCH; ++l) {
        float2 u2 = *(const float2*)(ub + l * IDIM + s2);
        #pragma unroll
        for (int ii = 0; ii < 4; ++ii) {
            h[0][ii] = h[0][ii] * a[0][ii] + u2.x;
            h[1][ii] = h[1][ii] * a[1][ii] + u2.y;
        }
    }
    #pragma unroll
    for (int ii = 0; ii < 4; ++ii) {
        float2 v;
        v.x = h[0][ii]; v.y = h[1][ii];
        *(float2*)&C_loc[(((size_t)b * NC + c) * IDIM + i4 + ii) * IDIM + s2] = v;
    }
}

// ---------------------------------------------------------------------------
// K4c2: fused seed + scan + contraction, s-quarter split. Wave = (b,c,q,ig),
// lane 2 s x 4 i, 8192 waves. Seed from C_loc carries (chunks < c, a^TCH).
// 4 l per reduce round. Writes patl plane (b*4+q) (non-atomic).
// ---------------------------------------------------------------------------
__global__ __launch_bounds__(256) void k4c2_pass2(const float* __restrict__ u,
                                                  const float* __restrict__ Cw,
                                                  const float* __restrict__ A,
                                                  const float* __restrict__ C_loc,
                                                  float* __restrict__ patl) {
    const int wave = (blockIdx.x * 256 + threadIdx.x) >> 6;  // 0..8191
    const int lane = threadIdx.x & 63;
    const int ig = wave & 127;
    const int q  = (wave >> 7) & (SQ - 1);
    const int c  = (wave >> 9) & (NC - 1);
    const int b  = wave >> 12;
    const int i4 = ig * 4;
    const int s2 = q * 128 + lane * 2;
    float a[2][4], h[2][4];
    #pragma unroll
    for (int k = 0; k < 2; ++k) {
        float4 av = *(const float4*)&A[(size_t)(s2 + k) * IDIM + i4];
        a[k][0] = av.x; a[k][1] = av.y; a[k][2] = av.z; a[k][3] = av.w;
        #pragma unroll
        for (int ii = 0; ii < 4; ++ii) h[k][ii] = 0.f;
    }
    if (c > 0) {
        float da[2][4];
        #pragma unroll
        for (int k = 0; k < 2; ++k)
            #pragma unroll
            for (int ii = 0; ii < 4; ++ii) {
                float aa = a[k][ii];
                aa = aa * aa; aa = aa * aa; aa = aa * aa;
                aa = aa * aa; aa = aa * aa;            // ^32 == TCH
                da[k][ii] = aa;
            }
        for (int cc = 0; cc < c; ++cc) {
            #pragma unroll
            for (int ii = 0; ii < 4; ++ii) {
                float2 cl = *(const float2*)&C_loc[(((size_t)b * NC + cc) * IDIM + i4 + ii) * IDIM + s2];
                h[0][ii] = h[0][ii] * da[0][ii] + cl.x;
                h[1][ii] = h[1][ii] * da[1][ii] + cl.y;
            }
        }
    }
    const float* ub = u + (size_t)b * LSEQ * IDIM;
    const float* cb = Cw + (size_t)b * LSEQ * IDIM;
    float* prow = patl + ((size_t)(b * SQ + q) * LSEQ) * IDIM;
    const bool w16 = ((lane & 15) == 0);
    const int iiw = lane >> 4;
    for (int l0 = c * TCH; l0 < c * TCH + TCH; l0 += 4) {
        float p[4][4];
        #pragma unroll
        for (int j = 0; j < 4; ++j) {
            const int l = l0 + j;
            float2 u2 = *(const float2*)(ub + l * IDIM + s2);
            float2 c2 = *(const float2*)(cb + l * IDIM + s2);
            #pragma unroll
            for (int ii = 0; ii < 4; ++ii) {
                h[0][ii] = h[0][ii] * a[0][ii] + u2.x;
                h[1][ii] = h[1][ii] * a[1][ii] + u2.y;
                p[j][ii] = c2.x * h[0][ii] + c2.y * h[1][ii];
            }
        }
        #pragma unroll
        for (int j = 0; j < 4; ++j)
            #pragma unroll
            for (int ii = 0; ii < 4; ++ii) p[j][ii] += __shfl_xor(p[j][ii], 16, 64);
        #pragma unroll
        for (int j = 0; j < 4; ++j)
            #pragma unroll
            for (int ii = 0; ii < 4; ++ii) p[j][ii] += __shfl_xor(p[j][ii], 32, 64);
        float qv[4];
        #pragma unroll
        for (int j = 0; j < 4; ++j)
            qv[j] = (lane & 32) ? ((lane & 16) ? p[j][3] : p[j][2])
                                : ((lane & 16) ? p[j][1] : p[j][0]);
        #pragma unroll
        for (int j = 0; j < 4; ++j) qv[j] += __shfl_xor(qv[j], 1, 64);
        #pragma unroll
        for (int j = 0; j < 4; ++j) qv[j] += __shfl_xor(qv[j], 2, 64);
        #pragma unroll
        for (int j = 0; j < 4; ++j) qv[j] += __shfl_xor(qv[j], 4, 64);
        #pragma unroll
        for (int j = 0; j < 4; ++j) qv[j] += __shfl_xor(qv[j], 8, 64);
        if (w16) {
            #pragma unroll
            for (int j = 0; j < 4; ++j)
                prow[(size_t)(l0 + j) * IDIM + i4 + iiw] = qv[j];
        }
    }
}

// ---------------------------------------------------------------------------
// k5a2: outlin = (y + patl0..3) @ W_out^T. Wave per 16x16 tile,
// 512 waves / 128 blocks. A-fragment built f32->bf16 in-registers.
// ---------------------------------------------------------------------------
__global__ __launch_bounds__(256) void k5a2_mfma(const float* __restrict__ y,
                                                 const float* __restrict__ patl,
                                                 const unsigned short* __restrict__ W_outb,
                                                 float* __restrict__ outlin) {
    const int t = threadIdx.x;
    const int w = blockIdx.x * 4 + (t >> 6);   // 0..511
    const int lane = t & 63;
    const int mt = w >> 4, nt = w & 15;
    const int r0 = mt * 16, h0 = nt * 16;
    const int fr = lane & 15, fk = (lane >> 4) * 8;
    const int r = r0 + fr;
    const int rb = r >> 8, rl = r & 255;
    const float* apf = y + (size_t)r * IDIM + fk;
    const float* p0f = patl + (((size_t)(rb * SQ + 0) * LSEQ + rl) * IDIM) + fk;
    const float* p1f = patl + (((size_t)(rb * SQ + 1) * LSEQ + rl) * IDIM) + fk;
    const float* p2f = patl + (((size_t)(rb * SQ + 2) * LSEQ + rl) * IDIM) + fk;
    const float* p3f = patl + (((size_t)(rb * SQ + 3) * LSEQ + rl) * IDIM) + fk;
    const unsigned short* bp = W_outb + (size_t)(h0 + fr) * IDIM + fk;
    f32x4 acc = {0.f, 0.f, 0.f, 0.f};
    #pragma unroll
    for (int k0 = 0; k0 < IDIM; k0 += 32) {
        float4 f0 = *(const float4*)(apf + k0);
        float4 f1 = *(const float4*)(apf + k0 + 4);
        float4 g0 = *(const float4*)(p0f + k0);
        float4 g1 = *(const float4*)(p0f + k0 + 4);
        float4 e0 = *(const float4*)(p1f + k0);
        float4 e1 = *(const float4*)(p1f + k0 + 4);
        float4 m0 = *(const float4*)(p2f + k0);
        float4 m1 = *(const float4*)(p2f + k0 + 4);
        float4 n0 = *(const float4*)(p3f + k0);
        float4 n1 = *(const float4*)(p3f + k0 + 4);
        bf16x8 av;
        av[0] = (short)f2b(f0.x + g0.x + e0.x + m0.x + n0.x);
        av[1] = (short)f2b(f0.y + g0.y + e0.y + m0.y + n0.y);
        av[2] = (short)f2b(f0.z + g0.z + e0.z + m0.z + n0.z);
        av[3] = (short)f2b(f0.w + g0.w + e0.w + m0.w + n0.w);
        av[4] = (short)f2b(f1.x + g1.x + e1.x + m1.x + n1.x);
        av[5] = (short)f2b(f1.y + g1.y + e1.y + m1.y + n1.y);
        av[6] = (short)f2b(f1.z + g1.z + e1.z + m1.z + n1.z);
        av[7] = (short)f2b(f1.w + g1.w + e1.w + m1.w + n1.w);
        bf16x8 bv = *(const bf16x8*)(bp + k0);
        acc = __builtin_amdgcn_mfma_f32_16x16x32_bf16(av, bv, acc, 0, 0, 0);
    }
    const int orow = (lane >> 4) * 4;
    const int hc = h0 + fr;
    #pragma unroll
    for (int j = 0; j < 4; ++j)
        outlin[(size_t)(r0 + orow + j) * HDIM + hc] = acc[j];
}

// ---------------------------------------------------------------------------
// K5b: LayerNorm over H=256 + z scale + residual. One block per row.
// ---------------------------------------------------------------------------
__global__ __launch_bounds__(256) void k5b_ln(const float* __restrict__ outlin,
                                              const float* __restrict__ x,
                                              const float* __restrict__ z,
                                              const float* __restrict__ ln_g,
                                              const float* __restrict__ ln_b,
                                              float* __restrict__ out) {
    const int r = blockIdx.x;
    const int t = threadIdx.x;
    float v = outlin[(size_t)r * HDIM + t];
    float s1 = v, s2 = v * v;
    #pragma unroll
    for (int off = 1; off < 64; off <<= 1) {
        s1 += __shfl_xor(s1, off, 64);
        s2 += __shfl_xor(s2, off, 64);
    }
    __shared__ float r1[4], r2[4];
    const int w = t >> 6, lane = t & 63;
    if (lane == 0) { r1[w] = s1; r2[w] = s2; }
    __syncthreads();
    float t1 = r1[0] + r1[1] + r1[2] + r1[3];
    float t2 = r2[0] + r2[1] + r2[2] + r2[3];
    float mu = t1 * (1.0f / 256.0f);
    float var = t2 * (1.0f / 256.0f) - mu * mu;
    float inv = rsqrtf(var + 1e-5f);
    float o = (v - mu) * inv * ln_g[t] + ln_b[t];
    out[(size_t)r * HDIM + t] = o * z[0] + x[(size_t)r * HDIM + t];
}

// ---------------------------------------------------------------------------
extern "C" void kernel_launch(void* const* d_in, const int* in_sizes, int n_in,
                              void* d_out, int out_size, void* d_ws, size_t ws_size,
                              hipStream_t stream) {
    const float* x      = (const float*)d_in[0];
    const float* W_in   = (const float*)d_in[1];
    const float* conv_w = (const float*)d_in[2];
    const float* conv_b = (const float*)d_in[3];
    const float* W_ssm  = (const float*)d_in[4];
    const float* b_ssm  = (const float*)d_in[5];
    const float* W_gate = (const float*)d_in[6];
    const float* b_gate = (const float*)d_in[7];
    const float* A      = (const float*)d_in[8];
    const float* D      = (const float*)d_in[9];
    const float* W_out  = (const float*)d_in[10];
    const float* z      = (const float*)d_in[11];
    const float* ln_g   = (const float*)d_in[12];
    const float* ln_b   = (const float*)d_in[13];
    float* out = (float*)d_out;

    float* ws = (float*)d_ws;
    float*          y      = ws;                               // 262144 f32
    float*          xc     = ws + 262144;                      // 262144 f32
    float*          Cw     = ws + 524288;                      // 262144 f32
    float*          u      = ws + 786432;                      // 262144 f32
    float*          patl   = ws + 1048576;                     // 1048576 f32 (4 planes/b)
    float*          outlin = ws + 2097152;                     // 131072 f32
    float*          bsg    = ws + 2228224;                     // 2048 f32
    unsigned short* Wsgb   = (unsigned short*)(ws + 2230272);  // 786432 bf16
    unsigned short* W_outb = (unsigned short*)(ws + 2623488);  // 131072 bf16
    // AREA: staging buffers dead by k4a; reused for C_loc
    float*          area   = ws + 2689024;                     // 4194304 f32
    unsigned short* xb     = (unsigned short*)area;            // 131072 bf16
    unsigned short* Wqb    = (unsigned short*)(area + 65536);  // 131072 bf16
    unsigned short* WgT    = (unsigned short*)(area + 131072); // 131072 bf16
    unsigned short* cwb    = (unsigned short*)(area + 196608); // 786432 bf16
    unsigned short* Wcb    = (unsigned short*)(area + 589824); // 393216 bf16
    unsigned short* xcb    = (unsigned short*)(area + 786432); // 262144 bf16
    float*          C_loc  = area;                             // 4194304 f32

    kcvt      <<<512, 256, 0, stream>>>(x, W_in, conv_w, W_ssm, W_gate, b_ssm,
                                        b_gate, W_out, xb, Wqb, WgT, cwb, Wsgb,
                                        bsg, W_outb);
    kW_mfma   <<<128, 256, 0, stream>>>(cwb, WgT, Wcb);
    kxc2_mfma <<<256, 256, 0, stream>>>(xb, Wqb, Wcb, conv_b, xc, xcb);
    k3f_mfma  <<<256, 256, 0, stream>>>(xcb, Wsgb, bsg, xc, D, Cw, u, y);
    k4a_pass1 <<<2048, 256, 0, stream>>>(u, A, C_loc);
    k4c2_pass2<<<2048, 256, 0, stream>>>(u, Cw, A, C_loc, patl);
    k5a2_mfma <<<128, 256, 0, stream>>>(y, patl, W_outb, outlin);
    k5b_ln    <<<512, 256, 0, stream>>>(outlin, x, z, ln_g, ln_b, out);
}

// Round 17
// 105.998 us; speedup vs baseline: 1.0812x; 1.0812x over previous
//
#include <hip/hip_runtime.h>
#include <math.h>

// Problem dims
#define NB    2
#define LSEQ  256
#define HDIM  256
#define IDIM  512
#define NROW  512      // NB*LSEQ
#define NC    8        // scan chunks
#define TCH   32       // chunk length (NC*TCH == LSEQ)

typedef __attribute__((ext_vector_type(8))) short bf16x8;
typedef __attribute__((ext_vector_type(4))) float f32x4;

__device__ inline unsigned short f2b(float f) {
    unsigned u = __float_as_uint(f);
    return (unsigned short)((u + 0x7FFFu + ((u >> 16) & 1u)) >> 16);
}

// ---------------------------------------------------------------------------
// kcvt: bf16 staging: xb[r][h], Wqb[o][h], WgT[h][i], cwb[k][o][i], Wsgb,
// bsg, W_outb. Memory-bound, grid-stride.
// ---------------------------------------------------------------------------
__global__ __launch_bounds__(256) void kcvt(const float* __restrict__ x,
                                            const float* __restrict__ W_in,
                                            const float* __restrict__ conv_w,
                                            const float* __restrict__ W_ssm,
                                            const float* __restrict__ W_gate,
                                            const float* __restrict__ b_ssm,
                                            const float* __restrict__ b_gate,
                                            const float* __restrict__ W_out,
                                            unsigned short* __restrict__ xb,
                                            unsigned short* __restrict__ Wqb,
                                            unsigned short* __restrict__ WgT,
                                            unsigned short* __restrict__ cwb,
                                            unsigned short* __restrict__ Wsgb,
                                            float* __restrict__ bsg,
                                            unsigned short* __restrict__ W_outb) {
    const int stride = gridDim.x * 256;
    const int t0 = blockIdx.x * 256 + threadIdx.x;
    for (int i = t0; i < 131072; i += stride) xb[i] = f2b(x[i]);
    for (int i = t0; i < 131072; i += stride) Wqb[i] = f2b(W_in[i]);
    // WgT[h][i] = W_in[512+i][h]
    for (int d = t0; d < 131072; d += stride) {
        int i = d & 511, h = d >> 9;
        WgT[(size_t)h * 512 + i] = f2b(W_in[(size_t)(512 + i) * 256 + h]);
    }
    // cwb[k][o][i] = conv_w[o][i][k]
    for (int d = t0; d < 262144; d += stride) {
        const float* s = conv_w + (size_t)d * 3;
        cwb[d]          = f2b(s[0]);
        cwb[262144 + d] = f2b(s[1]);
        cwb[524288 + d] = f2b(s[2]);
    }
    // Wsgb rows: 0..1023 = W_ssm[512..1535]; 1024..1535 = W_gate[512..1023]
    for (int d = t0; d < 786432; d += stride) {
        int j = d >> 9, i = d & 511;
        float v = (j < 1024) ? W_ssm[(size_t)(512 + j) * 512 + i]
                             : W_gate[(size_t)(j - 512) * 512 + i];
        Wsgb[d] = f2b(v);
    }
    for (int j = t0; j < 1536; j += stride)
        bsg[j] = (j < 1024) ? b_ssm[512 + j] : b_gate[j - 512];
    for (int i = t0; i < 131072; i += stride) W_outb[i] = f2b(W_out[i]);
}

// ---------------------------------------------------------------------------
// kW: Wcb[k][o][h] = sum_i cwb[k][o][i] * WgT[h][i]  (3 planes share B-frag).
// ---------------------------------------------------------------------------
__global__ __launch_bounds__(256) void kW_mfma(const unsigned short* __restrict__ cwb,
                                               const unsigned short* __restrict__ WgT,
                                               unsigned short* __restrict__ Wcb) {
    const int t = threadIdx.x;
    const int w = blockIdx.x * 4 + (t >> 6);   // 0..511
    const int lane = t & 63;
    const int mt = w >> 4, nt = w & 15;
    const int o0 = mt * 16, h0 = nt * 16;
    const int fr = lane & 15, fk = (lane >> 4) * 8;
    const unsigned short* a0 = cwb + (size_t)(o0 + fr) * 512 + fk;
    const unsigned short* a1 = a0 + 262144;
    const unsigned short* a2 = a0 + 524288;
    const unsigned short* bp = WgT + (size_t)(h0 + fr) * 512 + fk;
    f32x4 ac0 = {0.f, 0.f, 0.f, 0.f};
    f32x4 ac1 = {0.f, 0.f, 0.f, 0.f};
    f32x4 ac2 = {0.f, 0.f, 0.f, 0.f};
    #pragma unroll
    for (int k0 = 0; k0 < 512; k0 += 32) {
        bf16x8 bv = *(const bf16x8*)(bp + k0);
        bf16x8 v0 = *(const bf16x8*)(a0 + k0);
        bf16x8 v1 = *(const bf16x8*)(a1 + k0);
        bf16x8 v2 = *(const bf16x8*)(a2 + k0);
        ac0 = __builtin_amdgcn_mfma_f32_16x16x32_bf16(v0, bv, ac0, 0, 0, 0);
        ac1 = __builtin_amdgcn_mfma_f32_16x16x32_bf16(v1, bv, ac1, 0, 0, 0);
        ac2 = __builtin_amdgcn_mfma_f32_16x16x32_bf16(v2, bv, ac2, 0, 0, 0);
    }
    const int orow = (lane >> 4) * 4;
    const int hc = h0 + fr;
    #pragma unroll
    for (int j = 0; j < 4; ++j) {
        size_t o = (size_t)(o0 + orow + j) * 256 + hc;
        Wcb[o]          = f2b(ac0[j]);
        Wcb[131072 + o] = f2b(ac1[j]);
        Wcb[262144 + o] = f2b(ac2[j]);
    }
}

// ---------------------------------------------------------------------------
// kxc2: xc[r,o] = gelu(x_r·Wq[o]) + sum_k x_{r+k-1}·Wc[k][o] + conv_b[o]
// ---------------------------------------------------------------------------
__global__ __launch_bounds__(256) void kxc2_mfma(const unsigned short* __restrict__ xb,
                                                 const unsigned short* __restrict__ Wqb,
                                                 const unsigned short* __restrict__ Wcb,
                                                 const float* __restrict__ conv_b,
                                                 float* __restrict__ xc,
                                                 unsigned short* __restrict__ xcb) {
    const int t = threadIdx.x;
    const int w = blockIdx.x * 4 + (t >> 6);   // 0..1023
    const int lane = t & 63;
    const int mt = w >> 5, nt = w & 31;
    const int r0 = mt * 16, o0 = nt * 16;
    const int fr = lane & 15, fk = (lane >> 4) * 8;
    const int g = r0 + fr;
    const int lo = r0 & ~255, hi = lo + 256;
    const bool okm = (g - 1 >= lo), okp = (g + 1 < hi);
    const unsigned short* am = xb + (size_t)(g - 1) * 256 + fk;
    const unsigned short* a0 = xb + (size_t)g * 256 + fk;
    const unsigned short* ap = xb + (size_t)(g + 1) * 256 + fk;
    const unsigned short* bq = Wqb + (size_t)(o0 + fr) * 256 + fk;
    const unsigned short* b0 = Wcb + (size_t)(o0 + fr) * 256 + fk;
    const unsigned short* b1 = b0 + 131072;
    const unsigned short* b2 = b0 + 262144;
    const bf16x8 zz = {0, 0, 0, 0, 0, 0, 0, 0};
    f32x4 accq = {0.f, 0.f, 0.f, 0.f};
    f32x4 accc = {0.f, 0.f, 0.f, 0.f};
    #pragma unroll
    for (int k0 = 0; k0 < 256; k0 += 32) {
        bf16x8 avm = okm ? *(const bf16x8*)(am + k0) : zz;
        bf16x8 av0 = *(const bf16x8*)(a0 + k0);
        bf16x8 avp = okp ? *(const bf16x8*)(ap + k0) : zz;
        bf16x8 bqv = *(const bf16x8*)(bq + k0);
        bf16x8 b0v = *(const bf16x8*)(b0 + k0);
        bf16x8 b1v = *(const bf16x8*)(b1 + k0);
        bf16x8 b2v = *(const bf16x8*)(b2 + k0);
        accq = __builtin_amdgcn_mfma_f32_16x16x32_bf16(av0, bqv, accq, 0, 0, 0);
        accc = __builtin_amdgcn_mfma_f32_16x16x32_bf16(avm, b0v, accc, 0, 0, 0);
        accc = __builtin_amdgcn_mfma_f32_16x16x32_bf16(av0, b1v, accc, 0, 0, 0);
        accc = __builtin_amdgcn_mfma_f32_16x16x32_bf16(avp, b2v, accc, 0, 0, 0);
    }
    const int orow = (lane >> 4) * 4;
    const int oc = o0 + fr;
    const float cb = conv_b[oc];
    #pragma unroll
    for (int j = 0; j < 4; ++j) {
        int r = r0 + orow + j;
        float q = accq[j];
        float gl = 0.5f * q * (1.0f + erff(q * 0.70710678118654752f));
        float v = gl + accc[j] + cb;
        xc[(size_t)r * IDIM + oc] = v;
        xcb[(size_t)r * IDIM + oc] = f2b(v);
    }
}

// ---------------------------------------------------------------------------
// k3f: fused ssm/gate GEMM + elementwise; also pre-initializes y = u*D.
// ---------------------------------------------------------------------------
__global__ __launch_bounds__(256) void k3f_mfma(const unsigned short* __restrict__ xcb,
                                                const unsigned short* __restrict__ Wsgb,
                                                const float* __restrict__ bsg,
                                                const float* __restrict__ xc,
                                                const float* __restrict__ D,
                                                float* __restrict__ Cw,
                                                float* __restrict__ u,
                                                float* __restrict__ y) {
    const int t = threadIdx.x;
    const int w = blockIdx.x * 4 + (t >> 6);   // 0..1023
    const int lane = t & 63;
    const int mt = w >> 5, nt = w & 31;
    const int r0 = mt * 16, s0 = nt * 16;
    const int fr = lane & 15, fk = (lane >> 4) * 8;
    const unsigned short* ap = xcb + (size_t)(r0 + fr) * IDIM + fk;
    const unsigned short* b0 = Wsgb + (size_t)(s0 + fr) * IDIM + fk;
    const unsigned short* b1 = Wsgb + (size_t)(512 + s0 + fr) * IDIM + fk;
    const unsigned short* b2 = Wsgb + (size_t)(1024 + s0 + fr) * IDIM + fk;
    f32x4 ac0 = {0.f, 0.f, 0.f, 0.f};
    f32x4 ac1 = {0.f, 0.f, 0.f, 0.f};
    f32x4 ac2 = {0.f, 0.f, 0.f, 0.f};
    #pragma unroll
    for (int k0 = 0; k0 < IDIM; k0 += 32) {
        bf16x8 av  = *(const bf16x8*)(ap + k0);
        bf16x8 bv0 = *(const bf16x8*)(b0 + k0);
        bf16x8 bv1 = *(const bf16x8*)(b1 + k0);
        bf16x8 bv2 = *(const bf16x8*)(b2 + k0);
        ac0 = __builtin_amdgcn_mfma_f32_16x16x32_bf16(av, bv0, ac0, 0, 0, 0);
        ac1 = __builtin_amdgcn_mfma_f32_16x16x32_bf16(av, bv1, ac1, 0, 0, 0);
        ac2 = __builtin_amdgcn_mfma_f32_16x16x32_bf16(av, bv2, ac2, 0, 0, 0);
    }
    const int orow = (lane >> 4) * 4;
    const int sc = s0 + fr;
    const float bc = bsg[sc], bd = bsg[512 + sc], bg = bsg[1024 + sc];
    const float Dv = D[sc];
    #pragma unroll
    for (int j = 0; j < 4; ++j) {
        int r = r0 + orow + j;
        float craw = ac0[j] + bc;
        float dw   = ac1[j] + bd;
        float graw = ac2[j] + bg;
        float gv = 1.0f / (1.0f + expf(-graw));
        float xcv = xc[(size_t)r * IDIM + sc];
        float uv = xcv * dw * dw;
        Cw[(size_t)r * IDIM + sc] = gv * craw;
        u[(size_t)r * IDIM + sc]  = uv;
        y[(size_t)r * IDIM + sc]  = uv * Dv;
    }
}

// ---------------------------------------------------------------------------
// K4a: chunk-local scan, s-half split (R9 shape). Wave = (b,c,sh,ig): lane
// owns 4 s x 8 i. 2048 waves. Writes carry quarter to C_loc.
// ---------------------------------------------------------------------------
__global__ __launch_bounds__(256) void k4a_pass1(const float* __restrict__ u,
                                                 const float* __restrict__ A,
                                                 float* __restrict__ C_loc) {
    const int wave = (blockIdx.x * 256 + threadIdx.x) >> 6;  // 0..2047
    const int lane = threadIdx.x & 63;
    const int ig = wave & 63;
    const int sh = (wave >> 6) & 1;
    const int c  = (wave >> 7) & (NC - 1);
    const int b  = wave >> 10;
    const int i8 = ig * 8;
    const int s4 = sh * 256 + lane * 4;
    float a[4][8], h[4][8];
    #pragma unroll
    for (int k = 0; k < 4; ++k) {
        float4 a0 = *(const float4*)&A[(size_t)(s4 + k) * IDIM + i8];
        float4 a1 = *(const float4*)&A[(size_t)(s4 + k) * IDIM + i8 + 4];
        a[k][0] = a0.x; a[k][1] = a0.y; a[k][2] = a0.z; a[k][3] = a0.w;
        a[k][4] = a1.x; a[k][5] = a1.y; a[k][6] = a1.z; a[k][7] = a1.w;
        #pragma unroll
        for (int ii = 0; ii < 8; ++ii) h[k][ii] = 0.f;
    }
    const float* ub = u + ((size_t)b * LSEQ + c * TCH) * IDIM;
    for (int l = 0; l < TCH; ++l) {
        float4 u4 = *(const float4*)(ub + l * IDIM + s4);
        float uu[4] = {u4.x, u4.y, u4.z, u4.w};
        #pragma unroll
        for (int ii = 0; ii < 8; ++ii)
            #pragma unroll
            for (int k = 0; k < 4; ++k)
                h[k][ii] = h[k][ii] * a[k][ii] + uu[k];
    }
    #pragma unroll
    for (int ii = 0; ii < 8; ++ii) {
        float4 v;
        v.x = h[0][ii]; v.y = h[1][ii]; v.z = h[2][ii]; v.w = h[3][ii];
        *(float4*)&C_loc[(((size_t)b * NC + c) * IDIM + i8 + ii) * IDIM + s4] = v;
    }
}

// ---------------------------------------------------------------------------
// K4b: sequential combine IN-PLACE (R9 shape): C_loc[b][c] becomes the state
// ENTERING chunk c. Thread per (b,i,s4). Fully parallel over 131K threads.
// ---------------------------------------------------------------------------
__global__ __launch_bounds__(256) void k4b_combine(const float* __restrict__ A,
                                                   float* __restrict__ C_loc) {
    int idx = blockIdx.x * 256 + threadIdx.x;   // < 2*512*128
    int s4 = (idx & 127) * 4;
    int i  = (idx >> 7) & 511;
    int b  = idx >> 16;
    float da[4], h4[4] = {0.0f, 0.0f, 0.0f, 0.0f};
    #pragma unroll
    for (int j = 0; j < 4; ++j) {
        float aa = A[(size_t)(s4 + j) * IDIM + i];
        aa = aa * aa; aa = aa * aa; aa = aa * aa;
        aa = aa * aa; aa = aa * aa;                 // ^32 == TCH
        da[j] = aa;
    }
    for (int c = 0; c < NC; ++c) {
        size_t base = (((size_t)b * NC + c) * IDIM + i) * IDIM + s4;
        float4 cl = *(const float4*)&C_loc[base];   // carry of chunk c
        float4 hv;
        hv.x = h4[0]; hv.y = h4[1]; hv.z = h4[2]; hv.w = h4[3];
        *(float4*)&C_loc[base] = hv;                // state entering chunk c
        h4[0] = h4[0] * da[0] + cl.x;
        h4[1] = h4[1] * da[1] + cl.y;
        h4[2] = h4[2] * da[2] + cl.z;
        h4[3] = h4[3] * da[3] + cl.w;
    }
}

// ---------------------------------------------------------------------------
// K4c: seeded scan + contraction (R9 shape): seed read DIRECTLY from C_loc
// (8 independent float4 loads). Lane owns 4 s x 8 i; 27-shfl reduce per l.
// Writes per-half partial rows patl[(b*2+sh)]. 2048 waves.
// ---------------------------------------------------------------------------
__global__ __launch_bounds__(256) void k4c_pass2(const float* __restrict__ u,
                                                 const float* __restrict__ Cw,
                                                 const float* __restrict__ A,
                                                 const float* __restrict__ H,
                                                 float* __restrict__ patl) {
    const int wave = (blockIdx.x * 256 + threadIdx.x) >> 6;  // 0..2047
    const int lane = threadIdx.x & 63;
    const int ig = wave & 63;
    const int sh = (wave >> 6) & 1;
    const int c  = (wave >> 7) & (NC - 1);
    const int b  = wave >> 10;
    const int i8 = ig * 8;
    const int s4 = sh * 256 + lane * 4;
    float a[4][8], h[4][8];
    #pragma unroll
    for (int k = 0; k < 4; ++k) {
        float4 a0 = *(const float4*)&A[(size_t)(s4 + k) * IDIM + i8];
        float4 a1 = *(const float4*)&A[(size_t)(s4 + k) * IDIM + i8 + 4];
        a[k][0] = a0.x; a[k][1] = a0.y; a[k][2] = a0.z; a[k][3] = a0.w;
        a[k][4] = a1.x; a[k][5] = a1.y; a[k][6] = a1.z; a[k][7] = a1.w;
    }
    #pragma unroll
    for (int ii = 0; ii < 8; ++ii) {
        float4 hv = *(const float4*)&H[(((size_t)b * NC + c) * IDIM + i8 + ii) * IDIM + s4];
        h[0][ii] = hv.x; h[1][ii] = hv.y; h[2][ii] = hv.z; h[3][ii] = hv.w;
    }
    const float* ub = u + (size_t)b * LSEQ * IDIM;
    const float* cb = Cw + (size_t)b * LSEQ * IDIM;
    float* prow = patl + ((size_t)(b * 2 + sh) * LSEQ) * IDIM;
    const bool w8 = ((lane & 7) == 0);
    const int iiw = lane >> 3;
    for (int l = c * TCH; l < c * TCH + TCH; ++l) {
        float4 u4 = *(const float4*)(ub + l * IDIM + s4);
        float4 c4 = *(const float4*)(cb + l * IDIM + s4);
        float uu[4] = {u4.x, u4.y, u4.z, u4.w};
        float cc[4] = {c4.x, c4.y, c4.z, c4.w};
        float p[8];
        #pragma unroll
        for (int ii = 0; ii < 8; ++ii) {
            float acc = 0.f;
            #pragma unroll
            for (int k = 0; k < 4; ++k) {
                h[k][ii] = h[k][ii] * a[k][ii] + uu[k];
                acc += cc[k] * h[k][ii];
            }
            p[ii] = acc;
        }
        #pragma unroll
        for (int ii = 0; ii < 8; ++ii) p[ii] += __shfl_xor(p[ii], 8, 64);
        #pragma unroll
        for (int ii = 0; ii < 8; ++ii) p[ii] += __shfl_xor(p[ii], 16, 64);
        #pragma unroll
        for (int ii = 0; ii < 8; ++ii) p[ii] += __shfl_xor(p[ii], 32, 64);
        float q = (lane & 32) ? ((lane & 16) ? ((lane & 8) ? p[7] : p[6])
                                             : ((lane & 8) ? p[5] : p[4]))
                              : ((lane & 16) ? ((lane & 8) ? p[3] : p[2])
                                             : ((lane & 8) ? p[1] : p[0]));
        q += __shfl_xor(q, 1, 64);
        q += __shfl_xor(q, 2, 64);
        q += __shfl_xor(q, 4, 64);
        if (w8) prow[(size_t)l * IDIM + i8 + iiw] = q;
    }
}

// ---------------------------------------------------------------------------
// k5a2: outlin = (y + patl0 + patl1) @ W_out^T. Wave per 16x16 tile,
// 512 waves / 128 blocks. A-fragment built f32->bf16 in-registers.
// ---------------------------------------------------------------------------
__global__ __launch_bounds__(256) void k5a2_mfma(const float* __restrict__ y,
                                                 const float* __restrict__ patl,
                                                 const unsigned short* __restrict__ W_outb,
                                                 float* __restrict__ outlin) {
    const int t = threadIdx.x;
    const int w = blockIdx.x * 4 + (t >> 6);   // 0..511
    const int lane = t & 63;
    const int mt = w >> 4, nt = w & 15;
    const int r0 = mt * 16, h0 = nt * 16;
    const int fr = lane & 15, fk = (lane >> 4) * 8;
    const int r = r0 + fr;
    const int rb = r >> 8, rl = r & 255;
    const float* apf = y + (size_t)r * IDIM + fk;
    const float* p0f = patl + (((size_t)(rb * 2 + 0) * LSEQ + rl) * IDIM) + fk;
    const float* p1f = patl + (((size_t)(rb * 2 + 1) * LSEQ + rl) * IDIM) + fk;
    const unsigned short* bp = W_outb + (size_t)(h0 + fr) * IDIM + fk;
    f32x4 acc = {0.f, 0.f, 0.f, 0.f};
    #pragma unroll
    for (int k0 = 0; k0 < IDIM; k0 += 32) {
        float4 f0 = *(const float4*)(apf + k0);
        float4 f1 = *(const float4*)(apf + k0 + 4);
        float4 g0 = *(const float4*)(p0f + k0);
        float4 g1 = *(const float4*)(p0f + k0 + 4);
        float4 e0 = *(const float4*)(p1f + k0);
        float4 e1 = *(const float4*)(p1f + k0 + 4);
        bf16x8 av;
        av[0] = (short)f2b(f0.x + g0.x + e0.x);
        av[1] = (short)f2b(f0.y + g0.y + e0.y);
        av[2] = (short)f2b(f0.z + g0.z + e0.z);
        av[3] = (short)f2b(f0.w + g0.w + e0.w);
        av[4] = (short)f2b(f1.x + g1.x + e1.x);
        av[5] = (short)f2b(f1.y + g1.y + e1.y);
        av[6] = (short)f2b(f1.z + g1.z + e1.z);
        av[7] = (short)f2b(f1.w + g1.w + e1.w);
        bf16x8 bv = *(const bf16x8*)(bp + k0);
        acc = __builtin_amdgcn_mfma_f32_16x16x32_bf16(av, bv, acc, 0, 0, 0);
    }
    const int orow = (lane >> 4) * 4;
    const int hc = h0 + fr;
    #pragma unroll
    for (int j = 0; j < 4; ++j)
        outlin[(size_t)(r0 + orow + j) * HDIM + hc] = acc[j];
}

// ---------------------------------------------------------------------------
// K5b: LayerNorm over H=256 + z scale + residual. One block per row.
// ---------------------------------------------------------------------------
__global__ __launch_bounds__(256) void k5b_ln(const float* __restrict__ outlin,
                                              const float* __restrict__ x,
                                              const float* __restrict__ z,
                                              const float* __restrict__ ln_g,
                                              const float* __restrict__ ln_b,
                                              float* __restrict__ out) {
    const int r = blockIdx.x;
    const int t = threadIdx.x;
    float v = outlin[(size_t)r * HDIM + t];
    float s1 = v, s2 = v * v;
    #pragma unroll
    for (int off = 1; off < 64; off <<= 1) {
        s1 += __shfl_xor(s1, off, 64);
        s2 += __shfl_xor(s2, off, 64);
    }
    __shared__ float r1[4], r2[4];
    const int w = t >> 6, lane = t & 63;
    if (lane == 0) { r1[w] = s1; r2[w] = s2; }
    __syncthreads();
    float t1 = r1[0] + r1[1] + r1[2] + r1[3];
    float t2 = r2[0] + r2[1] + r2[2] + r2[3];
    float mu = t1 * (1.0f / 256.0f);
    float var = t2 * (1.0f / 256.0f) - mu * mu;
    float inv = rsqrtf(var + 1e-5f);
    float o = (v - mu) * inv * ln_g[t] + ln_b[t];
    out[(size_t)r * HDIM + t] = o * z[0] + x[(size_t)r * HDIM + t];
}

// ---------------------------------------------------------------------------
extern "C" void kernel_launch(void* const* d_in, const int* in_sizes, int n_in,
                              void* d_out, int out_size, void* d_ws, size_t ws_size,
                              hipStream_t stream) {
    const float* x      = (const float*)d_in[0];
    const float* W_in   = (const float*)d_in[1];
    const float* conv_w = (const float*)d_in[2];
    const float* conv_b = (const float*)d_in[3];
    const float* W_ssm  = (const float*)d_in[4];
    const float* b_ssm  = (const float*)d_in[5];
    const float* W_gate = (const float*)d_in[6];
    const float* b_gate = (const float*)d_in[7];
    const float* A      = (const float*)d_in[8];
    const float* D      = (const float*)d_in[9];
    const float* W_out  = (const float*)d_in[10];
    const float* z      = (const float*)d_in[11];
    const float* ln_g   = (const float*)d_in[12];
    const float* ln_b   = (const float*)d_in[13];
    float* out = (float*)d_out;

    float* ws = (float*)d_ws;
    float*          y      = ws;                               // 262144 f32
    float*          xc     = ws + 262144;                      // 262144 f32
    float*          Cw     = ws + 524288;                      // 262144 f32
    float*          u      = ws + 786432;                      // 262144 f32
    float*          patl   = ws + 1048576;                     // 524288 f32
    float*          outlin = ws + 1572864;                     // 131072 f32
    float*          bsg    = ws + 1703936;                     // 2048 f32
    unsigned short* Wsgb   = (unsigned short*)(ws + 1705984);  // 786432 bf16
    unsigned short* W_outb = (unsigned short*)(ws + 2099200);  // 131072 bf16
    // AREA: staging buffers dead by k4a; reused for C_loc
    float*          area   = ws + 2164736;                     // 4194304 f32
    unsigned short* xb     = (unsigned short*)area;            // 131072 bf16
    unsigned short* Wqb    = (unsigned short*)(area + 65536);  // 131072 bf16
    unsigned short* WgT    = (unsigned short*)(area + 131072); // 131072 bf16
    unsigned short* cwb    = (unsigned short*)(area + 196608); // 786432 bf16
    unsigned short* Wcb    = (unsigned short*)(area + 589824); // 393216 bf16
    unsigned short* xcb    = (unsigned short*)(area + 786432); // 262144 bf16
    float*          C_loc  = area;                             // 4194304 f32

    kcvt       <<<512, 256, 0, stream>>>(x, W_in, conv_w, W_ssm, W_gate, b_ssm,
                                         b_gate, W_out, xb, Wqb, WgT, cwb, Wsgb,
                                         bsg, W_outb);
    kW_mfma    <<<128, 256, 0, stream>>>(cwb, WgT, Wcb);
    kxc2_mfma  <<<256, 256, 0, stream>>>(xb, Wqb, Wcb, conv_b, xc, xcb);
    k3f_mfma   <<<256, 256, 0, stream>>>(xcb, Wsgb, bsg, xc, D, Cw, u, y);
    k4a_pass1  <<<512, 256, 0, stream>>>(u, A, C_loc);
    k4b_combine<<<512, 256, 0, stream>>>(A, C_loc);
    k4c_pass2  <<<512, 256, 0, stream>>>(u, Cw, A, C_loc, patl);
    k5a2_mfma  <<<128, 256, 0, stream>>>(y, patl, W_outb, outlin);
    k5b_ln     <<<512, 256, 0, stream>>>(outlin, x, z, ln_g, ln_b, out);
}

// Round 18
// 90.716 us; speedup vs baseline: 1.2634x; 1.1685x over previous
//
#include <hip/hip_runtime.h>
#include <math.h>

// Problem dims
#define NB    2
#define LSEQ  256
#define HDIM  256
#define IDIM  512
#define NROW  512      // NB*LSEQ
#define NC    8        // scan chunks
#define TCH   32       // chunk length (NC*TCH == LSEQ)

typedef __attribute__((ext_vector_type(8))) short bf16x8;
typedef __attribute__((ext_vector_type(4))) float f32x4;

__device__ inline unsigned short f2b(float f) {
    unsigned u = __float_as_uint(f);
    return (unsigned short)((u + 0x7FFFu + ((u >> 16) & 1u)) >> 16);
}

// ---------------------------------------------------------------------------
// kcvt: bf16 staging: xb[r][h], Wqb[o][h], WgT[h][i], cwb[k][o][i], Wsgb,
// bsg, W_outb. Memory-bound, grid-stride.
// ---------------------------------------------------------------------------
__global__ __launch_bounds__(256) void kcvt(const float* __restrict__ x,
                                            const float* __restrict__ W_in,
                                            const float* __restrict__ conv_w,
                                            const float* __restrict__ W_ssm,
                                            const float* __restrict__ W_gate,
                                            const float* __restrict__ b_ssm,
                                            const float* __restrict__ b_gate,
                                            const float* __restrict__ W_out,
                                            unsigned short* __restrict__ xb,
                                            unsigned short* __restrict__ Wqb,
                                            unsigned short* __restrict__ WgT,
                                            unsigned short* __restrict__ cwb,
                                            unsigned short* __restrict__ Wsgb,
                                            float* __restrict__ bsg,
                                            unsigned short* __restrict__ W_outb) {
    const int stride = gridDim.x * 256;
    const int t0 = blockIdx.x * 256 + threadIdx.x;
    for (int i = t0; i < 131072; i += stride) xb[i] = f2b(x[i]);
    for (int i = t0; i < 131072; i += stride) Wqb[i] = f2b(W_in[i]);
    // WgT[h][i] = W_in[512+i][h]
    for (int d = t0; d < 131072; d += stride) {
        int i = d & 511, h = d >> 9;
        WgT[(size_t)h * 512 + i] = f2b(W_in[(size_t)(512 + i) * 256 + h]);
    }
    // cwb[k][o][i] = conv_w[o][i][k]
    for (int d = t0; d < 262144; d += stride) {
        const float* s = conv_w + (size_t)d * 3;
        cwb[d]          = f2b(s[0]);
        cwb[262144 + d] = f2b(s[1]);
        cwb[524288 + d] = f2b(s[2]);
    }
    // Wsgb rows: 0..1023 = W_ssm[512..1535]; 1024..1535 = W_gate[512..1023]
    for (int d = t0; d < 786432; d += stride) {
        int j = d >> 9, i = d & 511;
        float v = (j < 1024) ? W_ssm[(size_t)(512 + j) * 512 + i]
                             : W_gate[(size_t)(j - 512) * 512 + i];
        Wsgb[d] = f2b(v);
    }
    for (int j = t0; j < 1536; j += stride)
        bsg[j] = (j < 1024) ? b_ssm[512 + j] : b_gate[j - 512];
    for (int i = t0; i < 131072; i += stride) W_outb[i] = f2b(W_out[i]);
}

// ---------------------------------------------------------------------------
// kW: Wcb[k][o][h] = sum_i cwb[k][o][i] * WgT[h][i]  (3 planes share B-frag).
// ---------------------------------------------------------------------------
__global__ __launch_bounds__(256) void kW_mfma(const unsigned short* __restrict__ cwb,
                                               const unsigned short* __restrict__ WgT,
                                               unsigned short* __restrict__ Wcb) {
    const int t = threadIdx.x;
    const int w = blockIdx.x * 4 + (t >> 6);   // 0..511
    const int lane = t & 63;
    const int mt = w >> 4, nt = w & 15;
    const int o0 = mt * 16, h0 = nt * 16;
    const int fr = lane & 15, fk = (lane >> 4) * 8;
    const unsigned short* a0 = cwb + (size_t)(o0 + fr) * 512 + fk;
    const unsigned short* a1 = a0 + 262144;
    const unsigned short* a2 = a0 + 524288;
    const unsigned short* bp = WgT + (size_t)(h0 + fr) * 512 + fk;
    f32x4 ac0 = {0.f, 0.f, 0.f, 0.f};
    f32x4 ac1 = {0.f, 0.f, 0.f, 0.f};
    f32x4 ac2 = {0.f, 0.f, 0.f, 0.f};
    #pragma unroll
    for (int k0 = 0; k0 < 512; k0 += 32) {
        bf16x8 bv = *(const bf16x8*)(bp + k0);
        bf16x8 v0 = *(const bf16x8*)(a0 + k0);
        bf16x8 v1 = *(const bf16x8*)(a1 + k0);
        bf16x8 v2 = *(const bf16x8*)(a2 + k0);
        ac0 = __builtin_amdgcn_mfma_f32_16x16x32_bf16(v0, bv, ac0, 0, 0, 0);
        ac1 = __builtin_amdgcn_mfma_f32_16x16x32_bf16(v1, bv, ac1, 0, 0, 0);
        ac2 = __builtin_amdgcn_mfma_f32_16x16x32_bf16(v2, bv, ac2, 0, 0, 0);
    }
    const int orow = (lane >> 4) * 4;
    const int hc = h0 + fr;
    #pragma unroll
    for (int j = 0; j < 4; ++j) {
        size_t o = (size_t)(o0 + orow + j) * 256 + hc;
        Wcb[o]          = f2b(ac0[j]);
        Wcb[131072 + o] = f2b(ac1[j]);
        Wcb[262144 + o] = f2b(ac2[j]);
    }
}

// ---------------------------------------------------------------------------
// kxc2: xc[r,o] = gelu(x_r·Wq[o]) + sum_k x_{r+k-1}·Wc[k][o] + conv_b[o]
// ---------------------------------------------------------------------------
__global__ __launch_bounds__(256) void kxc2_mfma(const unsigned short* __restrict__ xb,
                                                 const unsigned short* __restrict__ Wqb,
                                                 const unsigned short* __restrict__ Wcb,
                                                 const float* __restrict__ conv_b,
                                                 float* __restrict__ xc,
                                                 unsigned short* __restrict__ xcb) {
    const int t = threadIdx.x;
    const int w = blockIdx.x * 4 + (t >> 6);   // 0..1023
    const int lane = t & 63;
    const int mt = w >> 5, nt = w & 31;
    const int r0 = mt * 16, o0 = nt * 16;
    const int fr = lane & 15, fk = (lane >> 4) * 8;
    const int g = r0 + fr;
    const int lo = r0 & ~255, hi = lo + 256;
    const bool okm = (g - 1 >= lo), okp = (g + 1 < hi);
    const unsigned short* am = xb + (size_t)(g - 1) * 256 + fk;
    const unsigned short* a0 = xb + (size_t)g * 256 + fk;
    const unsigned short* ap = xb + (size_t)(g + 1) * 256 + fk;
    const unsigned short* bq = Wqb + (size_t)(o0 + fr) * 256 + fk;
    const unsigned short* b0 = Wcb + (size_t)(o0 + fr) * 256 + fk;
    const unsigned short* b1 = b0 + 131072;
    const unsigned short* b2 = b0 + 262144;
    const bf16x8 zz = {0, 0, 0, 0, 0, 0, 0, 0};
    f32x4 accq = {0.f, 0.f, 0.f, 0.f};
    f32x4 accc = {0.f, 0.f, 0.f, 0.f};
    #pragma unroll
    for (int k0 = 0; k0 < 256; k0 += 32) {
        bf16x8 avm = okm ? *(const bf16x8*)(am + k0) : zz;
        bf16x8 av0 = *(const bf16x8*)(a0 + k0);
        bf16x8 avp = okp ? *(const bf16x8*)(ap + k0) : zz;
        bf16x8 bqv = *(const bf16x8*)(bq + k0);
        bf16x8 b0v = *(const bf16x8*)(b0 + k0);
        bf16x8 b1v = *(const bf16x8*)(b1 + k0);
        bf16x8 b2v = *(const bf16x8*)(b2 + k0);
        accq = __builtin_amdgcn_mfma_f32_16x16x32_bf16(av0, bqv, accq, 0, 0, 0);
        accc = __builtin_amdgcn_mfma_f32_16x16x32_bf16(avm, b0v, accc, 0, 0, 0);
        accc = __builtin_amdgcn_mfma_f32_16x16x32_bf16(av0, b1v, accc, 0, 0, 0);
        accc = __builtin_amdgcn_mfma_f32_16x16x32_bf16(avp, b2v, accc, 0, 0, 0);
    }
    const int orow = (lane >> 4) * 4;
    const int oc = o0 + fr;
    const float cb = conv_b[oc];
    #pragma unroll
    for (int j = 0; j < 4; ++j) {
        int r = r0 + orow + j;
        float q = accq[j];
        float gl = 0.5f * q * (1.0f + erff(q * 0.70710678118654752f));
        float v = gl + accc[j] + cb;
        xc[(size_t)r * IDIM + oc] = v;
        xcb[(size_t)r * IDIM + oc] = f2b(v);
    }
}

// ---------------------------------------------------------------------------
// k3f: fused ssm/gate GEMM + elementwise; also pre-initializes y = u*D.
// ---------------------------------------------------------------------------
__global__ __launch_bounds__(256) void k3f_mfma(const unsigned short* __restrict__ xcb,
                                                const unsigned short* __restrict__ Wsgb,
                                                const float* __restrict__ bsg,
                                                const float* __restrict__ xc,
                                                const float* __restrict__ D,
                                                float* __restrict__ Cw,
                                                float* __restrict__ u,
                                                float* __restrict__ y) {
    const int t = threadIdx.x;
    const int w = blockIdx.x * 4 + (t >> 6);   // 0..1023
    const int lane = t & 63;
    const int mt = w >> 5, nt = w & 31;
    const int r0 = mt * 16, s0 = nt * 16;
    const int fr = lane & 15, fk = (lane >> 4) * 8;
    const unsigned short* ap = xcb + (size_t)(r0 + fr) * IDIM + fk;
    const unsigned short* b0 = Wsgb + (size_t)(s0 + fr) * IDIM + fk;
    const unsigned short* b1 = Wsgb + (size_t)(512 + s0 + fr) * IDIM + fk;
    const unsigned short* b2 = Wsgb + (size_t)(1024 + s0 + fr) * IDIM + fk;
    f32x4 ac0 = {0.f, 0.f, 0.f, 0.f};
    f32x4 ac1 = {0.f, 0.f, 0.f, 0.f};
    f32x4 ac2 = {0.f, 0.f, 0.f, 0.f};
    #pragma unroll
    for (int k0 = 0; k0 < IDIM; k0 += 32) {
        bf16x8 av  = *(const bf16x8*)(ap + k0);
        bf16x8 bv0 = *(const bf16x8*)(b0 + k0);
        bf16x8 bv1 = *(const bf16x8*)(b1 + k0);
        bf16x8 bv2 = *(const bf16x8*)(b2 + k0);
        ac0 = __builtin_amdgcn_mfma_f32_16x16x32_bf16(av, bv0, ac0, 0, 0, 0);
        ac1 = __builtin_amdgcn_mfma_f32_16x16x32_bf16(av, bv1, ac1, 0, 0, 0);
        ac2 = __builtin_amdgcn_mfma_f32_16x16x32_bf16(av, bv2, ac2, 0, 0, 0);
    }
    const int orow = (lane >> 4) * 4;
    const int sc = s0 + fr;
    const float bc = bsg[sc], bd = bsg[512 + sc], bg = bsg[1024 + sc];
    const float Dv = D[sc];
    #pragma unroll
    for (int j = 0; j < 4; ++j) {
        int r = r0 + orow + j;
        float craw = ac0[j] + bc;
        float dw   = ac1[j] + bd;
        float graw = ac2[j] + bg;
        float gv = 1.0f / (1.0f + expf(-graw));
        float xcv = xc[(size_t)r * IDIM + sc];
        float uv = xcv * dw * dw;
        Cw[(size_t)r * IDIM + sc] = gv * craw;
        u[(size_t)r * IDIM + sc]  = uv;
        y[(size_t)r * IDIM + sc]  = uv * Dv;
    }
}

// ---------------------------------------------------------------------------
// K4a: chunk-local scan. Wave = (b,c,sh,ig): lane owns 4 s x 4 i.
// 4096 waves (4/SIMD), 256-thr blocks, per-wave loads (R12-proven shape).
// ---------------------------------------------------------------------------
__global__ __launch_bounds__(256) void k4a_pass1(const float* __restrict__ u,
                                                 const float* __restrict__ A,
                                                 float* __restrict__ C_loc) {
    const int wave = (blockIdx.x * 256 + threadIdx.x) >> 6;  // 0..4095
    const int lane = threadIdx.x & 63;
    const int ig = wave & 127;
    const int sh = (wave >> 7) & 1;
    const int c  = (wave >> 8) & (NC - 1);
    const int b  = wave >> 11;
    const int i4 = ig * 4;
    const int s4 = sh * 256 + lane * 4;
    float a[4][4], h[4][4];
    #pragma unroll
    for (int k = 0; k < 4; ++k) {
        float4 av = *(const float4*)&A[(size_t)(s4 + k) * IDIM + i4];
        a[k][0] = av.x; a[k][1] = av.y; a[k][2] = av.z; a[k][3] = av.w;
        #pragma unroll
        for (int ii = 0; ii < 4; ++ii) h[k][ii] = 0.f;
    }
    const float* ub = u + ((size_t)b * LSEQ + c * TCH) * IDIM;
    for (int l = 0; l < TCH; ++l) {
        float4 u4 = *(const float4*)(ub + l * IDIM + s4);
        float uu[4] = {u4.x, u4.y, u4.z, u4.w};
        #pragma unroll
        for (int ii = 0; ii < 4; ++ii)
            #pragma unroll
            for (int k = 0; k < 4; ++k)
                h[k][ii] = h[k][ii] * a[k][ii] + uu[k];
    }
    #pragma unroll
    for (int ii = 0; ii < 4; ++ii) {
        float4 v;
        v.x = h[0][ii]; v.y = h[1][ii]; v.z = h[2][ii]; v.w = h[3][ii];
        *(float4*)&C_loc[(((size_t)b * NC + c) * IDIM + i4 + ii) * IDIM + s4] = v;
    }
}

// ---------------------------------------------------------------------------
// K4c2: fused seed + scan + contraction. Wave = (b,c,sh,ig), lane 4 s x 4 i.
// Seed computed as a WEIGHTED SUM over C_loc carries with software-pipelined
// independent loads: h_seed = sum_{cc<c} carry[cc] * da^(c-1-cc). Removes the
// R11 serial load->FMA->load chain. 4 l-steps per reduce round (12 shfl/l).
// Writes patl[b][sh] partial planes (non-atomic).
// ---------------------------------------------------------------------------
__global__ __launch_bounds__(256) void k4c2_pass2(const float* __restrict__ u,
                                                  const float* __restrict__ Cw,
                                                  const float* __restrict__ A,
                                                  const float* __restrict__ C_loc,
                                                  float* __restrict__ patl) {
    const int wave = (blockIdx.x * 256 + threadIdx.x) >> 6;  // 0..4095
    const int lane = threadIdx.x & 63;
    const int ig = wave & 127;
    const int sh = (wave >> 7) & 1;
    const int c  = (wave >> 8) & (NC - 1);
    const int b  = wave >> 11;
    const int i4 = ig * 4;
    const int s4 = sh * 256 + lane * 4;
    float a[4][4], h[4][4];
    #pragma unroll
    for (int k = 0; k < 4; ++k) {
        float4 av = *(const float4*)&A[(size_t)(s4 + k) * IDIM + i4];
        a[k][0] = av.x; a[k][1] = av.y; a[k][2] = av.z; a[k][3] = av.w;
        #pragma unroll
        for (int ii = 0; ii < 4; ++ii) h[k][ii] = 0.f;
    }
    if (c > 0) {
        float da[4][4], wgt[4][4];
        #pragma unroll
        for (int k = 0; k < 4; ++k)
            #pragma unroll
            for (int ii = 0; ii < 4; ++ii) {
                float aa = a[k][ii];
                aa = aa * aa; aa = aa * aa; aa = aa * aa;
                aa = aa * aa; aa = aa * aa;            // ^32 == TCH
                da[k][ii] = aa;
                wgt[k][ii] = 1.0f;
            }
        // software-pipelined weighted sum, descending cc (weights ascend)
        float4 cl[4];
        #pragma unroll
        for (int ii = 0; ii < 4; ++ii)
            cl[ii] = *(const float4*)&C_loc[(((size_t)b * NC + (c - 1)) * IDIM + i4 + ii) * IDIM + s4];
        for (int cc = c - 1; cc >= 0; --cc) {
            float4 nx[4];
            if (cc > 0) {
                #pragma unroll
                for (int ii = 0; ii < 4; ++ii)
                    nx[ii] = *(const float4*)&C_loc[(((size_t)b * NC + (cc - 1)) * IDIM + i4 + ii) * IDIM + s4];
            }
            #pragma unroll
            for (int ii = 0; ii < 4; ++ii) {
                h[0][ii] += cl[ii].x * wgt[0][ii];
                h[1][ii] += cl[ii].y * wgt[1][ii];
                h[2][ii] += cl[ii].z * wgt[2][ii];
                h[3][ii] += cl[ii].w * wgt[3][ii];
            }
            #pragma unroll
            for (int k = 0; k < 4; ++k)
                #pragma unroll
                for (int ii = 0; ii < 4; ++ii) wgt[k][ii] *= da[k][ii];
            if (cc > 0) {
                #pragma unroll
                for (int ii = 0; ii < 4; ++ii) cl[ii] = nx[ii];
            }
        }
    }
    const float* ub = u + (size_t)b * LSEQ * IDIM;
    const float* cb = Cw + (size_t)b * LSEQ * IDIM;
    float* prow = patl + ((size_t)(b * 2 + sh) * LSEQ) * IDIM;
    const bool w16 = ((lane & 15) == 0);
    const int iiw = lane >> 4;
    for (int l0 = c * TCH; l0 < c * TCH + TCH; l0 += 4) {
        float p[4][4];
        #pragma unroll
        for (int j = 0; j < 4; ++j) {
            const int l = l0 + j;
            float4 u4 = *(const float4*)(ub + l * IDIM + s4);
            float4 c4 = *(const float4*)(cb + l * IDIM + s4);
            float uu[4] = {u4.x, u4.y, u4.z, u4.w};
            float cc[4] = {c4.x, c4.y, c4.z, c4.w};
            #pragma unroll
            for (int ii = 0; ii < 4; ++ii) {
                float acc = 0.f;
                #pragma unroll
                for (int k = 0; k < 4; ++k) {
                    h[k][ii] = h[k][ii] * a[k][ii] + uu[k];
                    acc += cc[k] * h[k][ii];
                }
                p[j][ii] = acc;
            }
        }
        #pragma unroll
        for (int j = 0; j < 4; ++j)
            #pragma unroll
            for (int ii = 0; ii < 4; ++ii) p[j][ii] += __shfl_xor(p[j][ii], 16, 64);
        #pragma unroll
        for (int j = 0; j < 4; ++j)
            #pragma unroll
            for (int ii = 0; ii < 4; ++ii) p[j][ii] += __shfl_xor(p[j][ii], 32, 64);
        float q[4];
        #pragma unroll
        for (int j = 0; j < 4; ++j)
            q[j] = (lane & 32) ? ((lane & 16) ? p[j][3] : p[j][2])
                               : ((lane & 16) ? p[j][1] : p[j][0]);
        #pragma unroll
        for (int j = 0; j < 4; ++j) q[j] += __shfl_xor(q[j], 1, 64);
        #pragma unroll
        for (int j = 0; j < 4; ++j) q[j] += __shfl_xor(q[j], 2, 64);
        #pragma unroll
        for (int j = 0; j < 4; ++j) q[j] += __shfl_xor(q[j], 4, 64);
        #pragma unroll
        for (int j = 0; j < 4; ++j) q[j] += __shfl_xor(q[j], 8, 64);
        if (w16) {
            #pragma unroll
            for (int j = 0; j < 4; ++j)
                prow[(size_t)(l0 + j) * IDIM + i4 + iiw] = q[j];
        }
    }
}

// ---------------------------------------------------------------------------
// k5a2: outlin = (y + patl0 + patl1) @ W_out^T. Wave per 16x16 tile,
// 512 waves / 128 blocks. A-fragment built f32->bf16 in-registers.
// ---------------------------------------------------------------------------
__global__ __launch_bounds__(256) void k5a2_mfma(const float* __restrict__ y,
                                                 const float* __restrict__ patl,
                                                 const unsigned short* __restrict__ W_outb,
                                                 float* __restrict__ outlin) {
    const int t = threadIdx.x;
    const int w = blockIdx.x * 4 + (t >> 6);   // 0..511
    const int lane = t & 63;
    const int mt = w >> 4, nt = w & 15;
    const int r0 = mt * 16, h0 = nt * 16;
    const int fr = lane & 15, fk = (lane >> 4) * 8;
    const int r = r0 + fr;
    const int rb = r >> 8, rl = r & 255;
    const float* apf = y + (size_t)r * IDIM + fk;
    const float* p0f = patl + (((size_t)(rb * 2 + 0) * LSEQ + rl) * IDIM) + fk;
    const float* p1f = patl + (((size_t)(rb * 2 + 1) * LSEQ + rl) * IDIM) + fk;
    const unsigned short* bp = W_outb + (size_t)(h0 + fr) * IDIM + fk;
    f32x4 acc = {0.f, 0.f, 0.f, 0.f};
    #pragma unroll
    for (int k0 = 0; k0 < IDIM; k0 += 32) {
        float4 f0 = *(const float4*)(apf + k0);
        float4 f1 = *(const float4*)(apf + k0 + 4);
        float4 g0 = *(const float4*)(p0f + k0);
        float4 g1 = *(const float4*)(p0f + k0 + 4);
        float4 e0 = *(const float4*)(p1f + k0);
        float4 e1 = *(const float4*)(p1f + k0 + 4);
        bf16x8 av;
        av[0] = (short)f2b(f0.x + g0.x + e0.x);
        av[1] = (short)f2b(f0.y + g0.y + e0.y);
        av[2] = (short)f2b(f0.z + g0.z + e0.z);
        av[3] = (short)f2b(f0.w + g0.w + e0.w);
        av[4] = (short)f2b(f1.x + g1.x + e1.x);
        av[5] = (short)f2b(f1.y + g1.y + e1.y);
        av[6] = (short)f2b(f1.z + g1.z + e1.z);
        av[7] = (short)f2b(f1.w + g1.w + e1.w);
        bf16x8 bv = *(const bf16x8*)(bp + k0);
        acc = __builtin_amdgcn_mfma_f32_16x16x32_bf16(av, bv, acc, 0, 0, 0);
    }
    const int orow = (lane >> 4) * 4;
    const int hc = h0 + fr;
    #pragma unroll
    for (int j = 0; j < 4; ++j)
        outlin[(size_t)(r0 + orow + j) * HDIM + hc] = acc[j];
}

// ---------------------------------------------------------------------------
// K5b: LayerNorm over H=256 + z scale + residual. One block per row.
// ---------------------------------------------------------------------------
__global__ __launch_bounds__(256) void k5b_ln(const float* __restrict__ outlin,
                                              const float* __restrict__ x,
                                              const float* __restrict__ z,
                                              const float* __restrict__ ln_g,
                                              const float* __restrict__ ln_b,
                                              float* __restrict__ out) {
    const int r = blockIdx.x;
    const int t = threadIdx.x;
    float v = outlin[(size_t)r * HDIM + t];
    float s1 = v, s2 = v * v;
    #pragma unroll
    for (int off = 1; off < 64; off <<= 1) {
        s1 += __shfl_xor(s1, off, 64);
        s2 += __shfl_xor(s2, off, 64);
    }
    __shared__ float r1[4], r2[4];
    const int w = t >> 6, lane = t & 63;
    if (lane == 0) { r1[w] = s1; r2[w] = s2; }
    __syncthreads();
    float t1 = r1[0] + r1[1] + r1[2] + r1[3];
    float t2 = r2[0] + r2[1] + r2[2] + r2[3];
    float mu = t1 * (1.0f / 256.0f);
    float var = t2 * (1.0f / 256.0f) - mu * mu;
    float inv = rsqrtf(var + 1e-5f);
    float o = (v - mu) * inv * ln_g[t] + ln_b[t];
    out[(size_t)r * HDIM + t] = o * z[0] + x[(size_t)r * HDIM + t];
}

// ---------------------------------------------------------------------------
extern "C" void kernel_launch(void* const* d_in, const int* in_sizes, int n_in,
                              void* d_out, int out_size, void* d_ws, size_t ws_size,
                              hipStream_t stream) {
    const float* x      = (const float*)d_in[0];
    const float* W_in   = (const float*)d_in[1];
    const float* conv_w = (const float*)d_in[2];
    const float* conv_b = (const float*)d_in[3];
    const float* W_ssm  = (const float*)d_in[4];
    const float* b_ssm  = (const float*)d_in[5];
    const float* W_gate = (const float*)d_in[6];
    const float* b_gate = (const float*)d_in[7];
    const float* A      = (const float*)d_in[8];
    const float* D      = (const float*)d_in[9];
    const float* W_out  = (const float*)d_in[10];
    const float* z      = (const float*)d_in[11];
    const float* ln_g   = (const float*)d_in[12];
    const float* ln_b   = (const float*)d_in[13];
    float* out = (float*)d_out;

    float* ws = (float*)d_ws;
    float*          y      = ws;                               // 262144 f32
    float*          xc     = ws + 262144;                      // 262144 f32
    float*          Cw     = ws + 524288;                      // 262144 f32
    float*          u      = ws + 786432;                      // 262144 f32
    float*          patl   = ws + 1048576;                     // 524288 f32
    float*          outlin = ws + 1572864;                     // 131072 f32
    float*          bsg    = ws + 1703936;                     // 2048 f32
    unsigned short* Wsgb   = (unsigned short*)(ws + 1705984);  // 786432 bf16
    unsigned short* W_outb = (unsigned short*)(ws + 2099200);  // 131072 bf16
    // AREA: staging buffers dead by k4a; reused for C_loc
    float*          area   = ws + 2164736;                     // 4194304 f32
    unsigned short* xb     = (unsigned short*)area;            // 131072 bf16
    unsigned short* Wqb    = (unsigned short*)(area + 65536);  // 131072 bf16
    unsigned short* WgT    = (unsigned short*)(area + 131072); // 131072 bf16
    unsigned short* cwb    = (unsigned short*)(area + 196608); // 786432 bf16
    unsigned short* Wcb    = (unsigned short*)(area + 589824); // 393216 bf16
    unsigned short* xcb    = (unsigned short*)(area + 786432); // 262144 bf16
    float*          C_loc  = area;                             // 4194304 f32

    kcvt      <<<512, 256, 0, stream>>>(x, W_in, conv_w, W_ssm, W_gate, b_ssm,
                                        b_gate, W_out, xb, Wqb, WgT, cwb, Wsgb,
                                        bsg, W_outb);
    kW_mfma   <<<128, 256, 0, stream>>>(cwb, WgT, Wcb);
    kxc2_mfma <<<256, 256, 0, stream>>>(xb, Wqb, Wcb, conv_b, xc, xcb);
    k3f_mfma  <<<256, 256, 0, stream>>>(xcb, Wsgb, bsg, xc, D, Cw, u, y);
    k4a_pass1 <<<1024, 256, 0, stream>>>(u, A, C_loc);
    k4c2_pass2<<<1024, 256, 0, stream>>>(u, Cw, A, C_loc, patl);
    k5a2_mfma <<<128, 256, 0, stream>>>(y, patl, W_outb, outlin);
    k5b_ln    <<<512, 256, 0, stream>>>(outlin, x, z, ln_g, ln_b, out);
}

// Round 21
// 86.556 us; speedup vs baseline: 1.3241x; 1.0481x over previous
//
#include <hip/hip_runtime.h>
#include <math.h>

// Problem dims
#define NB    2
#define LSEQ  256
#define HDIM  256
#define IDIM  512
#define NROW  512      // NB*LSEQ
#define NC    8        // scan chunks
#define TCH   32       // chunk length (NC*TCH == LSEQ)

typedef __attribute__((ext_vector_type(8))) short bf16x8;
typedef __attribute__((ext_vector_type(4))) float f32x4;

__device__ inline unsigned short f2b(float f) {
    unsigned u = __float_as_uint(f);
    return (unsigned short)((u + 0x7FFFu + ((u >> 16) & 1u)) >> 16);
}

// DPP row_shr reduce step: lane i += lane (i-N) within its 16-lane row
// (0-fill via bound_ctrl). Row SUM accumulates into lane 15 of each row.
template <int CTRL>
__device__ inline float dpp_shr_add(float v) {
    int sh = __builtin_amdgcn_update_dpp(0, __float_as_int(v), CTRL, 0xF, 0xF, true);
    return v + __int_as_float(sh);
}

// ---------------------------------------------------------------------------
// kcvt: bf16 staging: xb[r][h], Wqb[o][h], WgT[h][i], cwb[k][o][i], Wsgb,
// bsg, W_outb. Memory-bound, grid-stride.
// ---------------------------------------------------------------------------
__global__ __launch_bounds__(256) void kcvt(const float* __restrict__ x,
                                            const float* __restrict__ W_in,
                                            const float* __restrict__ conv_w,
                                            const float* __restrict__ W_ssm,
                                            const float* __restrict__ W_gate,
                                            const float* __restrict__ b_ssm,
                                            const float* __restrict__ b_gate,
                                            const float* __restrict__ W_out,
                                            unsigned short* __restrict__ xb,
                                            unsigned short* __restrict__ Wqb,
                                            unsigned short* __restrict__ WgT,
                                            unsigned short* __restrict__ cwb,
                                            unsigned short* __restrict__ Wsgb,
                                            float* __restrict__ bsg,
                                            unsigned short* __restrict__ W_outb) {
    const int stride = gridDim.x * 256;
    const int t0 = blockIdx.x * 256 + threadIdx.x;
    for (int i = t0; i < 131072; i += stride) xb[i] = f2b(x[i]);
    for (int i = t0; i < 131072; i += stride) Wqb[i] = f2b(W_in[i]);
    // WgT[h][i] = W_in[512+i][h]
    for (int d = t0; d < 131072; d += stride) {
        int i = d & 511, h = d >> 9;
        WgT[(size_t)h * 512 + i] = f2b(W_in[(size_t)(512 + i) * 256 + h]);
    }
    // cwb[k][o][i] = conv_w[o][i][k]
    for (int d = t0; d < 262144; d += stride) {
        const float* s = conv_w + (size_t)d * 3;
        cwb[d]          = f2b(s[0]);
        cwb[262144 + d] = f2b(s[1]);
        cwb[524288 + d] = f2b(s[2]);
    }
    // Wsgb rows: 0..1023 = W_ssm[512..1535]; 1024..1535 = W_gate[512..1023]
    for (int d = t0; d < 786432; d += stride) {
        int j = d >> 9, i = d & 511;
        float v = (j < 1024) ? W_ssm[(size_t)(512 + j) * 512 + i]
                             : W_gate[(size_t)(j - 512) * 512 + i];
        Wsgb[d] = f2b(v);
    }
    for (int j = t0; j < 1536; j += stride)
        bsg[j] = (j < 1024) ? b_ssm[512 + j] : b_gate[j - 512];
    for (int i = t0; i < 131072; i += stride) W_outb[i] = f2b(W_out[i]);
}

// ---------------------------------------------------------------------------
// kW: Wcb[k][o][h] = sum_i cwb[k][o][i] * WgT[h][i]  (3 planes share B-frag).
// ---------------------------------------------------------------------------
__global__ __launch_bounds__(256) void kW_mfma(const unsigned short* __restrict__ cwb,
                                               const unsigned short* __restrict__ WgT,
                                               unsigned short* __restrict__ Wcb) {
    const int t = threadIdx.x;
    const int w = blockIdx.x * 4 + (t >> 6);   // 0..511
    const int lane = t & 63;
    const int mt = w >> 4, nt = w & 15;
    const int o0 = mt * 16, h0 = nt * 16;
    const int fr = lane & 15, fk = (lane >> 4) * 8;
    const unsigned short* a0 = cwb + (size_t)(o0 + fr) * 512 + fk;
    const unsigned short* a1 = a0 + 262144;
    const unsigned short* a2 = a0 + 524288;
    const unsigned short* bp = WgT + (size_t)(h0 + fr) * 512 + fk;
    f32x4 ac0 = {0.f, 0.f, 0.f, 0.f};
    f32x4 ac1 = {0.f, 0.f, 0.f, 0.f};
    f32x4 ac2 = {0.f, 0.f, 0.f, 0.f};
    #pragma unroll
    for (int k0 = 0; k0 < 512; k0 += 32) {
        bf16x8 bv = *(const bf16x8*)(bp + k0);
        bf16x8 v0 = *(const bf16x8*)(a0 + k0);
        bf16x8 v1 = *(const bf16x8*)(a1 + k0);
        bf16x8 v2 = *(const bf16x8*)(a2 + k0);
        ac0 = __builtin_amdgcn_mfma_f32_16x16x32_bf16(v0, bv, ac0, 0, 0, 0);
        ac1 = __builtin_amdgcn_mfma_f32_16x16x32_bf16(v1, bv, ac1, 0, 0, 0);
        ac2 = __builtin_amdgcn_mfma_f32_16x16x32_bf16(v2, bv, ac2, 0, 0, 0);
    }
    const int orow = (lane >> 4) * 4;
    const int hc = h0 + fr;
    #pragma unroll
    for (int j = 0; j < 4; ++j) {
        size_t o = (size_t)(o0 + orow + j) * 256 + hc;
        Wcb[o]          = f2b(ac0[j]);
        Wcb[131072 + o] = f2b(ac1[j]);
        Wcb[262144 + o] = f2b(ac2[j]);
    }
}

// ---------------------------------------------------------------------------
// kxc2: xc[r,o] = gelu(x_r·Wq[o]) + sum_k x_{r+k-1}·Wc[k][o] + conv_b[o]
// ---------------------------------------------------------------------------
__global__ __launch_bounds__(256) void kxc2_mfma(const unsigned short* __restrict__ xb,
                                                 const unsigned short* __restrict__ Wqb,
                                                 const unsigned short* __restrict__ Wcb,
                                                 const float* __restrict__ conv_b,
                                                 float* __restrict__ xc,
                                                 unsigned short* __restrict__ xcb) {
    const int t = threadIdx.x;
    const int w = blockIdx.x * 4 + (t >> 6);   // 0..1023
    const int lane = t & 63;
    const int mt = w >> 5, nt = w & 31;
    const int r0 = mt * 16, o0 = nt * 16;
    const int fr = lane & 15, fk = (lane >> 4) * 8;
    const int g = r0 + fr;
    const int lo = r0 & ~255, hi = lo + 256;
    const bool okm = (g - 1 >= lo), okp = (g + 1 < hi);
    const unsigned short* am = xb + (size_t)(g - 1) * 256 + fk;
    const unsigned short* a0 = xb + (size_t)g * 256 + fk;
    const unsigned short* ap = xb + (size_t)(g + 1) * 256 + fk;
    const unsigned short* bq = Wqb + (size_t)(o0 + fr) * 256 + fk;
    const unsigned short* b0 = Wcb + (size_t)(o0 + fr) * 256 + fk;
    const unsigned short* b1 = b0 + 131072;
    const unsigned short* b2 = b0 + 262144;
    const bf16x8 zz = {0, 0, 0, 0, 0, 0, 0, 0};
    f32x4 accq = {0.f, 0.f, 0.f, 0.f};
    f32x4 accc = {0.f, 0.f, 0.f, 0.f};
    #pragma unroll
    for (int k0 = 0; k0 < 256; k0 += 32) {
        bf16x8 avm = okm ? *(const bf16x8*)(am + k0) : zz;
        bf16x8 av0 = *(const bf16x8*)(a0 + k0);
        bf16x8 avp = okp ? *(const bf16x8*)(ap + k0) : zz;
        bf16x8 bqv = *(const bf16x8*)(bq + k0);
        bf16x8 b0v = *(const bf16x8*)(b0 + k0);
        bf16x8 b1v = *(const bf16x8*)(b1 + k0);
        bf16x8 b2v = *(const bf16x8*)(b2 + k0);
        accq = __builtin_amdgcn_mfma_f32_16x16x32_bf16(av0, bqv, accq, 0, 0, 0);
        accc = __builtin_amdgcn_mfma_f32_16x16x32_bf16(avm, b0v, accc, 0, 0, 0);
        accc = __builtin_amdgcn_mfma_f32_16x16x32_bf16(av0, b1v, accc, 0, 0, 0);
        accc = __builtin_amdgcn_mfma_f32_16x16x32_bf16(avp, b2v, accc, 0, 0, 0);
    }
    const int orow = (lane >> 4) * 4;
    const int oc = o0 + fr;
    const float cb = conv_b[oc];
    #pragma unroll
    for (int j = 0; j < 4; ++j) {
        int r = r0 + orow + j;
        float q = accq[j];
        float gl = 0.5f * q * (1.0f + erff(q * 0.70710678118654752f));
        float v = gl + accc[j] + cb;
        xc[(size_t)r * IDIM + oc] = v;
        xcb[(size_t)r * IDIM + oc] = f2b(v);
    }
}

// ---------------------------------------------------------------------------
// k3f: fused ssm/gate GEMM + elementwise; also pre-initializes y = u*D.
// ---------------------------------------------------------------------------
__global__ __launch_bounds__(256) void k3f_mfma(const unsigned short* __restrict__ xcb,
                                                const unsigned short* __restrict__ Wsgb,
                                                const float* __restrict__ bsg,
                                                const float* __restrict__ xc,
                                                const float* __restrict__ D,
                                                float* __restrict__ Cw,
                                                float* __restrict__ u,
                                                float* __restrict__ y) {
    const int t = threadIdx.x;
    const int w = blockIdx.x * 4 + (t >> 6);   // 0..1023
    const int lane = t & 63;
    const int mt = w >> 5, nt = w & 31;
    const int r0 = mt * 16, s0 = nt * 16;
    const int fr = lane & 15, fk = (lane >> 4) * 8;
    const unsigned short* ap = xcb + (size_t)(r0 + fr) * IDIM + fk;
    const unsigned short* b0 = Wsgb + (size_t)(s0 + fr) * IDIM + fk;
    const unsigned short* b1 = Wsgb + (size_t)(512 + s0 + fr) * IDIM + fk;
    const unsigned short* b2 = Wsgb + (size_t)(1024 + s0 + fr) * IDIM + fk;
    f32x4 ac0 = {0.f, 0.f, 0.f, 0.f};
    f32x4 ac1 = {0.f, 0.f, 0.f, 0.f};
    f32x4 ac2 = {0.f, 0.f, 0.f, 0.f};
    #pragma unroll
    for (int k0 = 0; k0 < IDIM; k0 += 32) {
        bf16x8 av  = *(const bf16x8*)(ap + k0);
        bf16x8 bv0 = *(const bf16x8*)(b0 + k0);
        bf16x8 bv1 = *(const bf16x8*)(b1 + k0);
        bf16x8 bv2 = *(const bf16x8*)(b2 + k0);
        ac0 = __builtin_amdgcn_mfma_f32_16x16x32_bf16(av, bv0, ac0, 0, 0, 0);
        ac1 = __builtin_amdgcn_mfma_f32_16x16x32_bf16(av, bv1, ac1, 0, 0, 0);
        ac2 = __builtin_amdgcn_mfma_f32_16x16x32_bf16(av, bv2, ac2, 0, 0, 0);
    }
    const int orow = (lane >> 4) * 4;
    const int sc = s0 + fr;
    const float bc = bsg[sc], bd = bsg[512 + sc], bg = bsg[1024 + sc];
    const float Dv = D[sc];
    #pragma unroll
    for (int j = 0; j < 4; ++j) {
        int r = r0 + orow + j;
        float craw = ac0[j] + bc;
        float dw   = ac1[j] + bd;
        float graw = ac2[j] + bg;
        float gv = 1.0f / (1.0f + expf(-graw));
        float xcv = xc[(size_t)r * IDIM + sc];
        float uv = xcv * dw * dw;
        Cw[(size_t)r * IDIM + sc] = gv * craw;
        u[(size_t)r * IDIM + sc]  = uv;
        y[(size_t)r * IDIM + sc]  = uv * Dv;
    }
}

// ---------------------------------------------------------------------------
// K4a: chunk-local scan. Wave = (b,c,sh,ig): lane owns 4 s x 4 i.
// 4096 waves (4/SIMD), 256-thr blocks, per-wave loads (R12-proven shape).
// ---------------------------------------------------------------------------
__global__ __launch_bounds__(256) void k4a_pass1(const float* __restrict__ u,
                                                 const float* __restrict__ A,
                                                 float* __restrict__ C_loc) {
    const int wave = (blockIdx.x * 256 + threadIdx.x) >> 6;  // 0..4095
    const int lane = threadIdx.x & 63;
    const int ig = wave & 127;
    const int sh = (wave >> 7) & 1;
    const int c  = (wave >> 8) & (NC - 1);
    const int b  = wave >> 11;
    const int i4 = ig * 4;
    const int s4 = sh * 256 + lane * 4;
    float a[4][4], h[4][4];
    #pragma unroll
    for (int k = 0; k < 4; ++k) {
        float4 av = *(const float4*)&A[(size_t)(s4 + k) * IDIM + i4];
        a[k][0] = av.x; a[k][1] = av.y; a[k][2] = av.z; a[k][3] = av.w;
        #pragma unroll
        for (int ii = 0; ii < 4; ++ii) h[k][ii] = 0.f;
    }
    const float* ub = u + ((size_t)b * LSEQ + c * TCH) * IDIM;
    for (int l = 0; l < TCH; ++l) {
        float4 u4 = *(const float4*)(ub + l * IDIM + s4);
        float uu[4] = {u4.x, u4.y, u4.z, u4.w};
        #pragma unroll
        for (int ii = 0; ii < 4; ++ii)
            #pragma unroll
            for (int k = 0; k < 4; ++k)
                h[k][ii] = h[k][ii] * a[k][ii] + uu[k];
    }
    #pragma unroll
    for (int ii = 0; ii < 4; ++ii) {
        float4 v;
        v.x = h[0][ii]; v.y = h[1][ii]; v.z = h[2][ii]; v.w = h[3][ii];
        *(float4*)&C_loc[(((size_t)b * NC + c) * IDIM + i4 + ii) * IDIM + s4] = v;
    }
}

// ---------------------------------------------------------------------------
// K4c2: fused seed + scan + contraction. Wave = (b,c,sh,ig), lane 4 s x 4 i.
// Seed: pipelined weighted sum over C_loc carries. Reduce per 4-l round:
// stageA = 2 shfl_xor (16,32); select; stageB = DPP row_shr chain (VALU) --
// row sum lands in lane 15 of each 16-lane row.
// Writes patl[b][sh] partial planes (non-atomic).
// ---------------------------------------------------------------------------
__global__ __launch_bounds__(256) void k4c2_pass2(const float* __restrict__ u,
                                                  const float* __restrict__ Cw,
                                                  const float* __restrict__ A,
                                                  const float* __restrict__ C_loc,
                                                  float* __restrict__ patl) {
    const int wave = (blockIdx.x * 256 + threadIdx.x) >> 6;  // 0..4095
    const int lane = threadIdx.x & 63;
    const int ig = wave & 127;
    const int sh = (wave >> 7) & 1;
    const int c  = (wave >> 8) & (NC - 1);
    const int b  = wave >> 11;
    const int i4 = ig * 4;
    const int s4 = sh * 256 + lane * 4;
    float a[4][4], h[4][4];
    #pragma unroll
    for (int k = 0; k < 4; ++k) {
        float4 av = *(const float4*)&A[(size_t)(s4 + k) * IDIM + i4];
        a[k][0] = av.x; a[k][1] = av.y; a[k][2] = av.z; a[k][3] = av.w;
        #pragma unroll
        for (int ii = 0; ii < 4; ++ii) h[k][ii] = 0.f;
    }
    if (c > 0) {
        float da[4][4], wgt[4][4];
        #pragma unroll
        for (int k = 0; k < 4; ++k)
            #pragma unroll
            for (int ii = 0; ii < 4; ++ii) {
                float aa = a[k][ii];
                aa = aa * aa; aa = aa * aa; aa = aa * aa;
                aa = aa * aa; aa = aa * aa;            // ^32 == TCH
                da[k][ii] = aa;
                wgt[k][ii] = 1.0f;
            }
        float4 cl[4];
        #pragma unroll
        for (int ii = 0; ii < 4; ++ii)
            cl[ii] = *(const float4*)&C_loc[(((size_t)b * NC + (c - 1)) * IDIM + i4 + ii) * IDIM + s4];
        for (int cc = c - 1; cc >= 0; --cc) {
            float4 nx[4];
            if (cc > 0) {
                #pragma unroll
                for (int ii = 0; ii < 4; ++ii)
                    nx[ii] = *(const float4*)&C_loc[(((size_t)b * NC + (cc - 1)) * IDIM + i4 + ii) * IDIM + s4];
            }
            #pragma unroll
            for (int ii = 0; ii < 4; ++ii) {
                h[0][ii] += cl[ii].x * wgt[0][ii];
                h[1][ii] += cl[ii].y * wgt[1][ii];
                h[2][ii] += cl[ii].z * wgt[2][ii];
                h[3][ii] += cl[ii].w * wgt[3][ii];
            }
            #pragma unroll
            for (int k = 0; k < 4; ++k)
                #pragma unroll
                for (int ii = 0; ii < 4; ++ii) wgt[k][ii] *= da[k][ii];
            if (cc > 0) {
                #pragma unroll
                for (int ii = 0; ii < 4; ++ii) cl[ii] = nx[ii];
            }
        }
    }
    const float* ub = u + (size_t)b * LSEQ * IDIM;
    const float* cb = Cw + (size_t)b * LSEQ * IDIM;
    float* prow = patl + ((size_t)(b * 2 + sh) * LSEQ) * IDIM;
    const bool w16 = ((lane & 15) == 15);   // DPP row sum lands in row lane 15
    const int iiw = lane >> 4;
    for (int l0 = c * TCH; l0 < c * TCH + TCH; l0 += 4) {
        float p[4][4];
        #pragma unroll
        for (int j = 0; j < 4; ++j) {
            const int l = l0 + j;
            float4 u4 = *(const float4*)(ub + l * IDIM + s4);
            float4 c4 = *(const float4*)(cb + l * IDIM + s4);
            float uu[4] = {u4.x, u4.y, u4.z, u4.w};
            float cc[4] = {c4.x, c4.y, c4.z, c4.w};
            #pragma unroll
            for (int ii = 0; ii < 4; ++ii) {
                float acc = 0.f;
                #pragma unroll
                for (int k = 0; k < 4; ++k) {
                    h[k][ii] = h[k][ii] * a[k][ii] + uu[k];
                    acc += cc[k] * h[k][ii];
                }
                p[j][ii] = acc;
            }
        }
        // stage A: sum out lane bits 4,5 (butterfly, cross-row)
        #pragma unroll
        for (int j = 0; j < 4; ++j)
            #pragma unroll
            for (int ii = 0; ii < 4; ++ii) p[j][ii] += __shfl_xor(p[j][ii], 16, 64);
        #pragma unroll
        for (int j = 0; j < 4; ++j)
            #pragma unroll
            for (int ii = 0; ii < 4; ++ii) p[j][ii] += __shfl_xor(p[j][ii], 32, 64);
        // select: 16-lane row g handles ii=g
        float q[4];
        #pragma unroll
        for (int j = 0; j < 4; ++j)
            q[j] = (lane & 32) ? ((lane & 16) ? p[j][3] : p[j][2])
                               : ((lane & 16) ? p[j][1] : p[j][0]);
        // stage B: DPP row_shr reduce within 16-lane rows (sum -> row lane 15)
        #pragma unroll
        for (int j = 0; j < 4; ++j) q[j] = dpp_shr_add<0x118>(q[j]);  // shr 8
        #pragma unroll
        for (int j = 0; j < 4; ++j) q[j] = dpp_shr_add<0x114>(q[j]);  // shr 4
        #pragma unroll
        for (int j = 0; j < 4; ++j) q[j] = dpp_shr_add<0x112>(q[j]);  // shr 2
        #pragma unroll
        for (int j = 0; j < 4; ++j) q[j] = dpp_shr_add<0x111>(q[j]);  // shr 1
        if (w16) {
            #pragma unroll
            for (int j = 0; j < 4; ++j)
                prow[(size_t)(l0 + j) * IDIM + i4 + iiw] = q[j];
        }
    }
}

// ---------------------------------------------------------------------------
// k5a2: outlin = (y + patl0 + patl1) @ W_out^T. Wave per 16x16 tile,
// 512 waves / 128 blocks. A-fragment built f32->bf16 in-registers.
// ---------------------------------------------------------------------------
__global__ __launch_bounds__(256) void k5a2_mfma(const float* __restrict__ y,
                                                 const float* __restrict__ patl,
                                                 const unsigned short* __restrict__ W_outb,
                                                 float* __restrict__ outlin) {
    const int t = threadIdx.x;
    const int w = blockIdx.x * 4 + (t >> 6);   // 0..511
    const int lane = t & 63;
    const int mt = w >> 4, nt = w & 15;
    const int r0 = mt * 16, h0 = nt * 16;
    const int fr = lane & 15, fk = (lane >> 4) * 8;
    const int r = r0 + fr;
    const int rb = r >> 8, rl = r & 255;
    const float* apf = y + (size_t)r * IDIM + fk;
    const float* p0f = patl + (((size_t)(rb * 2 + 0) * LSEQ + rl) * IDIM) + fk;
    const float* p1f = patl + (((size_t)(rb * 2 + 1) * LSEQ + rl) * IDIM) + fk;
    const unsigned short* bp = W_outb + (size_t)(h0 + fr) * IDIM + fk;
    f32x4 acc = {0.f, 0.f, 0.f, 0.f};
    #pragma unroll
    for (int k0 = 0; k0 < IDIM; k0 += 32) {
        float4 f0 = *(const float4*)(apf + k0);
        float4 f1 = *(const float4*)(apf + k0 + 4);
        float4 g0 = *(const float4*)(p0f + k0);
        float4 g1 = *(const float4*)(p0f + k0 + 4);
        float4 e0 = *(const float4*)(p1f + k0);
        float4 e1 = *(const float4*)(p1f + k0 + 4);
        bf16x8 av;
        av[0] = (short)f2b(f0.x + g0.x + e0.x);
        av[1] = (short)f2b(f0.y + g0.y + e0.y);
        av[2] = (short)f2b(f0.z + g0.z + e0.z);
        av[3] = (short)f2b(f0.w + g0.w + e0.w);
        av[4] = (short)f2b(f1.x + g1.x + e1.x);
        av[5] = (short)f2b(f1.y + g1.y + e1.y);
        av[6] = (short)f2b(f1.z + g1.z + e1.z);
        av[7] = (short)f2b(f1.w + g1.w + e1.w);
        bf16x8 bv = *(const bf16x8*)(bp + k0);
        acc = __builtin_amdgcn_mfma_f32_16x16x32_bf16(av, bv, acc, 0, 0, 0);
    }
    const int orow = (lane >> 4) * 4;
    const int hc = h0 + fr;
    #pragma unroll
    for (int j = 0; j < 4; ++j)
        outlin[(size_t)(r0 + orow + j) * HDIM + hc] = acc[j];
}

// ---------------------------------------------------------------------------
// K5b: LayerNorm over H=256 + z scale + residual. One block per row.
// ---------------------------------------------------------------------------
__global__ __launch_bounds__(256) void k5b_ln(const float* __restrict__ outlin,
                                              const float* __restrict__ x,
                                              const float* __restrict__ z,
                                              const float* __restrict__ ln_g,
                                              const float* __restrict__ ln_b,
                                              float* __restrict__ out) {
    const int r = blockIdx.x;
    const int t = threadIdx.x;
    float v = outlin[(size_t)r * HDIM + t];
    float s1 = v, s2 = v * v;
    #pragma unroll
    for (int off = 1; off < 64; off <<= 1) {
        s1 += __shfl_xor(s1, off, 64);
        s2 += __shfl_xor(s2, off, 64);
    }
    __shared__ float r1[4], r2[4];
    const int w = t >> 6, lane = t & 63;
    if (lane == 0) { r1[w] = s1; r2[w] = s2; }
    __syncthreads();
    float t1 = r1[0] + r1[1] + r1[2] + r1[3];
    float t2 = r2[0] + r2[1] + r2[2] + r2[3];
    float mu = t1 * (1.0f / 256.0f);
    float var = t2 * (1.0f / 256.0f) - mu * mu;
    float inv = rsqrtf(var + 1e-5f);
    float o = (v - mu) * inv * ln_g[t] + ln_b[t];
    out[(size_t)r * HDIM + t] = o * z[0] + x[(size_t)r * HDIM + t];
}

// ---------------------------------------------------------------------------
extern "C" void kernel_launch(void* const* d_in, const int* in_sizes, int n_in,
                              void* d_out, int out_size, void* d_ws, size_t ws_size,
                              hipStream_t stream) {
    const float* x      = (const float*)d_in[0];
    const float* W_in   = (const float*)d_in[1];
    const float* conv_w = (const float*)d_in[2];
    const float* conv_b = (const float*)d_in[3];
    const float* W_ssm  = (const float*)d_in[4];
    const float* b_ssm  = (const float*)d_in[5];
    const float* W_gate = (const float*)d_in[6];
    const float* b_gate = (const float*)d_in[7];
    const float* A      = (const float*)d_in[8];
    const float* D      = (const float*)d_in[9];
    const float* W_out  = (const float*)d_in[10];
    const float* z      = (const float*)d_in[11];
    const float* ln_g   = (const float*)d_in[12];
    const float* ln_b   = (const float*)d_in[13];
    float* out = (float*)d_out;

    float* ws = (float*)d_ws;
    float*          y      = ws;                               // 262144 f32
    float*          xc     = ws + 262144;                      // 262144 f32
    float*          Cw     = ws + 524288;                      // 262144 f32
    float*          u      = ws + 786432;                      // 262144 f32
    float*          patl   = ws + 1048576;                     // 524288 f32
    float*          outlin = ws + 1572864;                     // 131072 f32
    float*          bsg    = ws + 1703936;                     // 2048 f32
    unsigned short* Wsgb   = (unsigned short*)(ws + 1705984);  // 786432 bf16
    unsigned short* W_outb = (unsigned short*)(ws + 2099200);  // 131072 bf16
    // AREA: staging buffers dead by k4a; reused for C_loc
    float*          area   = ws + 2164736;                     // 4194304 f32
    unsigned short* xb     = (unsigned short*)area;            // 131072 bf16
    unsigned short* Wqb    = (unsigned short*)(area + 65536);  // 131072 bf16
    unsigned short* WgT    = (unsigned short*)(area + 131072); // 131072 bf16
    unsigned short* cwb    = (unsigned short*)(area + 196608); // 786432 bf16
    unsigned short* Wcb    = (unsigned short*)(area + 589824); // 393216 bf16
    unsigned short* xcb    = (unsigned short*)(area + 786432); // 262144 bf16
    float*          C_loc  = area;                             // 4194304 f32

    kcvt      <<<512, 256, 0, stream>>>(x, W_in, conv_w, W_ssm, W_gate, b_ssm,
                                        b_gate, W_out, xb, Wqb, WgT, cwb, Wsgb,
                                        bsg, W_outb);
    kW_mfma   <<<128, 256, 0, stream>>>(cwb, WgT, Wcb);
    kxc2_mfma <<<256, 256, 0, stream>>>(xb, Wqb, Wcb, conv_b, xc, xcb);
    k3f_mfma  <<<256, 256, 0, stream>>>(xcb, Wsgb, bsg, xc, D, Cw, u, y);
    k4a_pass1 <<<1024, 256, 0, stream>>>(u, A, C_loc);
    k4c2_pass2<<<1024, 256, 0, stream>>>(u, Cw, A, C_loc, patl);
    k5a2_mfma <<<128, 256, 0, stream>>>(y, patl, W_outb, outlin);
    k5b_ln    <<<512, 256, 0, stream>>>(outlin, x, z, ln_g, ln_b, out);
}